// Round 8
// baseline (927.922 us; speedup 1.0000x reference)
//
#include <hip/hip_runtime.h>
#include <math.h>

// ---------------------------------------------------------------------------
// GATNet pipeline, MI355X round 7: round 6 + fix — __shfl hoisted out of the
// lane-divergent ternary (ds_bpermute from inactive source lanes is undefined).
// ---------------------------------------------------------------------------

typedef __bf16 bf16x8 __attribute__((ext_vector_type(8)));
typedef __bf16 bf16x4 __attribute__((ext_vector_type(4)));
typedef __bf16 bf16x2 __attribute__((ext_vector_type(2)));
typedef float  f32x4  __attribute__((ext_vector_type(4)));
typedef short  short8 __attribute__((ext_vector_type(8)));

static __device__ __forceinline__ float leaky02(float e){ return e >= 0.f ? e : 0.2f*e; }

static __device__ __forceinline__ float wred_sum(float v){
  #pragma unroll
  for (int m = 1; m < 64; m <<= 1) v += __shfl_xor(v, m);
  return v;
}
static __device__ __forceinline__ float wred_max(float v){
  #pragma unroll
  for (int m = 1; m < 64; m <<= 1) v = fmaxf(v, __shfl_xor(v, m));
  return v;
}

// ---------- column sum-of-squares, f32 input (stage 1 on x only) ----------
__global__ void colnorm_sq(const float* __restrict__ X, float* __restrict__ ss, int R, int C){
  int c = blockIdx.x*blockDim.x + threadIdx.x;
  if (c >= C) return;
  int r0 = blockIdx.y * 128;
  int r1 = r0 + 128; if (r1 > R) r1 = R;
  float s = 0.f;
  for (int r = r0; r < r1; ++r){ float v = X[(size_t)r*C + c]; s = fmaf(v, v, s); }
  atomicAdd(&ss[c], s);
}

// ---------- l2norm-scale + split + transpose: W[K][N] -> TH/TL [N][K] bf16 ----------
__global__ __launch_bounds__(256) void split_tr_scaled(const float* __restrict__ B,
    const float* __restrict__ ss,
    __bf16* __restrict__ TH, __bf16* __restrict__ TL, int K, int N){
  __shared__ float tile[32][33];
  int lx = threadIdx.x & 31, ly = threadIdx.x >> 5;
  int kb = blockIdx.y*32, nb = blockIdx.x*32;
  #pragma unroll
  for (int i = 0; i < 4; i++){
    int kr = kb + ly + i*8;
    float inv = 1.f / fmaxf(sqrtf(ss[kr]), 1e-12f);
    tile[ly + i*8][lx] = B[(size_t)kr*N + nb + lx] * inv;
  }
  __syncthreads();
  #pragma unroll
  for (int i = 0; i < 4; i++){
    int nl = ly + i*8;
    float v = tile[lx][nl];
    __bf16 h = (__bf16)v;
    TH[(size_t)(nb + nl)*K + kb + lx] = h;
    TL[(size_t)(nb + nl)*K + kb + lx] = (__bf16)(v - (float)h);
  }
}

// ---------- split-bf16 MFMA GEMM, A pre-split bf16 (3-term) ----------
__global__ __launch_bounds__(256) void gemm_bf16x3(
    const __bf16* __restrict__ Ah, const __bf16* __restrict__ Al,
    const __bf16* __restrict__ Bth, const __bf16* __restrict__ Btl,
    float* __restrict__ C, int M, int N, int K)
{
  __shared__ __align__(16) __bf16 sAh[128][40];
  __shared__ __align__(16) __bf16 sAl[128][40];
  __shared__ __align__(16) __bf16 sBh[64][40];
  __shared__ __align__(16) __bf16 sBl[64][40];
  int tid = threadIdx.x;
  int lane = tid & 63, wave = tid >> 6;
  int wr = wave >> 1, wc = wave & 1;
  int rowBase = blockIdx.x << 7, colBase = blockIdx.y << 6;

  int ar = tid >> 2;
  int ac = tid & 3;

  short8 rAh0, rAh1, rAl0, rAl1, rBh, rBl;
  auto loadA = [&](int k0){
    rAh0 = *(const short8*)(Ah + (size_t)(rowBase + ar     )*K + k0 + ac*8);
    rAh1 = *(const short8*)(Ah + (size_t)(rowBase + ar + 64)*K + k0 + ac*8);
    rAl0 = *(const short8*)(Al + (size_t)(rowBase + ar     )*K + k0 + ac*8);
    rAl1 = *(const short8*)(Al + (size_t)(rowBase + ar + 64)*K + k0 + ac*8);
    rBh  = *(const short8*)(Bth + (size_t)(colBase + ar)*K + k0 + ac*8);
    rBl  = *(const short8*)(Btl + (size_t)(colBase + ar)*K + k0 + ac*8);
  };

  f32x4 acc[4][2];
  #pragma unroll
  for (int m = 0; m < 4; m++)
    #pragma unroll
    for (int n = 0; n < 2; n++) acc[m][n] = (f32x4){0.f,0.f,0.f,0.f};

  loadA(0);
  int nsteps = K >> 5;
  for (int s = 0; s < nsteps; ++s){
    __syncthreads();
    *(short8*)&sAh[ar][ac*8]      = rAh0;
    *(short8*)&sAh[ar+64][ac*8]   = rAh1;
    *(short8*)&sAl[ar][ac*8]      = rAl0;
    *(short8*)&sAl[ar+64][ac*8]   = rAl1;
    *(short8*)&sBh[ar][ac*8]      = rBh;
    *(short8*)&sBl[ar][ac*8]      = rBl;
    if (s + 1 < nsteps) loadA((s+1) << 5);
    __syncthreads();

    int kslot = lane >> 4;
    bf16x8 fah[4], fal[4], fbh[2], fbl[2];
    #pragma unroll
    for (int m = 0; m < 4; m++){
      int r = wr*64 + m*16 + (lane & 15);
      fah[m] = *(const bf16x8*)&sAh[r][kslot*8];
      fal[m] = *(const bf16x8*)&sAl[r][kslot*8];
    }
    #pragma unroll
    for (int n = 0; n < 2; n++){
      int c = wc*32 + n*16 + (lane & 15);
      fbh[n] = *(const bf16x8*)&sBh[c][kslot*8];
      fbl[n] = *(const bf16x8*)&sBl[c][kslot*8];
    }
    #pragma unroll
    for (int m = 0; m < 4; m++)
      #pragma unroll
      for (int n = 0; n < 2; n++){
        acc[m][n] = __builtin_amdgcn_mfma_f32_16x16x32_bf16(fah[m], fbh[n], acc[m][n], 0,0,0);
        acc[m][n] = __builtin_amdgcn_mfma_f32_16x16x32_bf16(fah[m], fbl[n], acc[m][n], 0,0,0);
        acc[m][n] = __builtin_amdgcn_mfma_f32_16x16x32_bf16(fal[m], fbh[n], acc[m][n], 0,0,0);
      }
  }

  int rg = lane >> 4, cl = lane & 15;
  #pragma unroll
  for (int m = 0; m < 4; m++)
    #pragma unroll
    for (int n = 0; n < 2; n++)
      #pragma unroll
      for (int j = 0; j < 4; j++)
        C[(size_t)(rowBase + wr*64 + m*16 + rg*4 + j)*N + colBase + wc*32 + n*16 + cl] = acc[m][n][j];
}

// ---------- same GEMM but A is f32 (stage 1: reads x directly, splits in-reg) ----------
__global__ __launch_bounds__(256) void gemm_f32a_bf16x3(
    const float* __restrict__ A,
    const __bf16* __restrict__ Bth, const __bf16* __restrict__ Btl,
    float* __restrict__ C, int M, int N, int K)
{
  __shared__ __align__(16) __bf16 sAh[128][40];
  __shared__ __align__(16) __bf16 sAl[128][40];
  __shared__ __align__(16) __bf16 sBh[64][40];
  __shared__ __align__(16) __bf16 sBl[64][40];
  int tid = threadIdx.x;
  int lane = tid & 63, wave = tid >> 6;
  int wr = wave >> 1, wc = wave & 1;
  int rowBase = blockIdx.x << 7, colBase = blockIdx.y << 6;

  int ar = tid >> 2;
  int ac = tid & 3;

  float4 rA0a, rA0b, rA1a, rA1b; short8 rBh, rBl;
  auto loadA = [&](int k0){
    const float* p0 = A + (size_t)(rowBase + ar)*K + k0 + ac*8;
    rA0a = *(const float4*)p0; rA0b = *(const float4*)(p0 + 4);
    const float* p1 = A + (size_t)(rowBase + ar + 64)*K + k0 + ac*8;
    rA1a = *(const float4*)p1; rA1b = *(const float4*)(p1 + 4);
    rBh  = *(const short8*)(Bth + (size_t)(colBase + ar)*K + k0 + ac*8);
    rBl  = *(const short8*)(Btl + (size_t)(colBase + ar)*K + k0 + ac*8);
  };
  auto splitst = [&](float4 a, float4 b, __bf16* dh, __bf16* dl){
    float t[8] = {a.x,a.y,a.z,a.w,b.x,b.y,b.z,b.w};
    bf16x8 hv, lv;
    #pragma unroll
    for (int j = 0; j < 8; j++){
      __bf16 h = (__bf16)t[j]; hv[j] = h; lv[j] = (__bf16)(t[j] - (float)h);
    }
    *(bf16x8*)dh = hv; *(bf16x8*)dl = lv;
  };

  f32x4 acc[4][2];
  #pragma unroll
  for (int m = 0; m < 4; m++)
    #pragma unroll
    for (int n = 0; n < 2; n++) acc[m][n] = (f32x4){0.f,0.f,0.f,0.f};

  loadA(0);
  int nsteps = K >> 5;
  for (int s = 0; s < nsteps; ++s){
    __syncthreads();
    splitst(rA0a, rA0b, &sAh[ar][ac*8],    &sAl[ar][ac*8]);
    splitst(rA1a, rA1b, &sAh[ar+64][ac*8], &sAl[ar+64][ac*8]);
    *(short8*)&sBh[ar][ac*8] = rBh;
    *(short8*)&sBl[ar][ac*8] = rBl;
    if (s + 1 < nsteps) loadA((s+1) << 5);
    __syncthreads();

    int kslot = lane >> 4;
    bf16x8 fah[4], fal[4], fbh[2], fbl[2];
    #pragma unroll
    for (int m = 0; m < 4; m++){
      int r = wr*64 + m*16 + (lane & 15);
      fah[m] = *(const bf16x8*)&sAh[r][kslot*8];
      fal[m] = *(const bf16x8*)&sAl[r][kslot*8];
    }
    #pragma unroll
    for (int n = 0; n < 2; n++){
      int c = wc*32 + n*16 + (lane & 15);
      fbh[n] = *(const bf16x8*)&sBh[c][kslot*8];
      fbl[n] = *(const bf16x8*)&sBl[c][kslot*8];
    }
    #pragma unroll
    for (int m = 0; m < 4; m++)
      #pragma unroll
      for (int n = 0; n < 2; n++){
        acc[m][n] = __builtin_amdgcn_mfma_f32_16x16x32_bf16(fah[m], fbh[n], acc[m][n], 0,0,0);
        acc[m][n] = __builtin_amdgcn_mfma_f32_16x16x32_bf16(fah[m], fbl[n], acc[m][n], 0,0,0);
        acc[m][n] = __builtin_amdgcn_mfma_f32_16x16x32_bf16(fal[m], fbh[n], acc[m][n], 0,0,0);
      }
  }

  int rg = lane >> 4, cl = lane & 15;
  #pragma unroll
  for (int m = 0; m < 4; m++)
    #pragma unroll
    for (int n = 0; n < 2; n++)
      #pragma unroll
      for (int j = 0; j < 4; j++)
        C[(size_t)(rowBase + wr*64 + m*16 + rg*4 + j)*N + colBase + wc*32 + n*16 + cl] = acc[m][n][j];
}

// ---------- fused: GAT attention coefficients (wave/node) + degree count ----------
__global__ __launch_bounds__(256) void att_deg_kernel(const float* __restrict__ h,
    const float* __restrict__ att_src, const float* __restrict__ att_dst,
    float* __restrict__ asrc, float* __restrict__ adst,
    const int* __restrict__ dst, int* __restrict__ deg, int nAttBlk, int E){
  if ((int)blockIdx.x < nAttBlk){
    int lane = threadIdx.x & 63;
    int node = blockIdx.x*4 + (threadIdx.x >> 6);
    const float4* hp = (const float4*)(h + (size_t)node*512);
    float4 v0 = hp[lane], v1 = hp[64 + lane];
    float4 as0 = ((const float4*)att_src)[lane], as1 = ((const float4*)att_src)[64+lane];
    float4 ad0 = ((const float4*)att_dst)[lane], ad1 = ((const float4*)att_dst)[64+lane];
    float s0 = v0.x*as0.x + v0.y*as0.y + v0.z*as0.z + v0.w*as0.w;
    float s1 = v1.x*as1.x + v1.y*as1.y + v1.z*as1.z + v1.w*as1.w;
    float d0 = v0.x*ad0.x + v0.y*ad0.y + v0.z*ad0.z + v0.w*ad0.w;
    float d1 = v1.x*ad1.x + v1.y*ad1.y + v1.z*ad1.z + v1.w*ad1.w;
    s0 = wred_sum(s0); s1 = wred_sum(s1); d0 = wred_sum(d0); d1 = wred_sum(d1);
    if (lane == 0){
      asrc[2*node] = s0; asrc[2*node+1] = s1;
      adst[2*node] = d0; adst[2*node+1] = d1;
    }
  } else {
    int e = (blockIdx.x - nAttBlk)*256 + threadIdx.x;
    if (e < E) atomicAdd(&deg[dst[e]], 1);
  }
}

// ---------- CSR build ----------
__global__ __launch_bounds__(1024) void scan_kernel(const int* __restrict__ deg,
    int* __restrict__ offs, int* __restrict__ cursor, int n){
  __shared__ int part[1024];
  int t = threadIdx.x;
  int chunk = (n + 1023) >> 10;
  int base = t * chunk;
  int loc[32];
  int local = 0;
  for (int k = 0; k < chunk; k++){
    int idx = base + k; loc[k] = local;
    if (idx < n) local += deg[idx] + 1;       // +1 self-loop
  }
  part[t] = local; __syncthreads();
  for (int off = 1; off < 1024; off <<= 1){
    int v = (t >= off) ? part[t-off] : 0; __syncthreads();
    part[t] += v; __syncthreads();
  }
  int excl = part[t] - local;
  for (int k = 0; k < chunk; k++){
    int idx = base + k;
    if (idx < n){ int o = excl + loc[k]; offs[idx] = o; cursor[idx] = o; }
  }
  if (t == 1023) offs[n] = part[1023];
}
__global__ void scatter_edges(const int* __restrict__ src, const int* __restrict__ dst,
                              int* cursor, int* __restrict__ ssrc, int E, int N){
  int e = blockIdx.x*blockDim.x + threadIdx.x;
  if (e < E){
    int d = dst[e]; int pos = atomicAdd(&cursor[d], 1); ssrc[pos] = src[e];
  } else if (e < E + N){
    int i = e - E; int pos = atomicAdd(&cursor[i], 1); ssrc[pos] = i;
  }
}

// ---------- GAT aggregation: wave per node, x4-unrolled gather, fused ss ----------
__global__ __launch_bounds__(256) void gat_aggregate_w(const float* __restrict__ h,
    const int* __restrict__ offs, const int* __restrict__ ssrc,
    const float* __restrict__ asrc, const float* __restrict__ adst,
    const float* __restrict__ bias,
    __bf16* __restrict__ H, __bf16* __restrict__ L,
    float* __restrict__ ssOut, int N){
  __shared__ float sq[4][512];
  int lane = threadIdx.x & 63, wid = threadIdx.x >> 6;
  int d = blockIdx.x*4 + wid;
  int beg = offs[d], end = offs[d+1], cnt = end - beg;
  float ad0 = adst[2*d], ad1 = adst[2*d+1];

  int dbase = lane*8;                 // this lane owns dims dbase..dbase+7
  bool head0 = dbase < 256;
  f32x4 acc0 = {0.f,0.f,0.f,0.f}, acc1 = {0.f,0.f,0.f,0.f};

  // x4-unrolled weighted gather. NOTE: every __shfl is executed by the FULL
  // wave (hoisted out of the head0 ternary) — ds_bpermute from a source lane
  // that is inactive under a divergent branch returns undefined data.
  auto gather = [&](int sreg, float al0, float al1, int cc){
    int o = 0;
    for (; o + 4 <= cc; o += 4){
      int s_0 = __shfl(sreg, o+0), s_1 = __shfl(sreg, o+1);
      int s_2 = __shfl(sreg, o+2), s_3 = __shfl(sreg, o+3);
      float a00 = __shfl(al0, o+0), a10 = __shfl(al1, o+0);
      float a01 = __shfl(al0, o+1), a11 = __shfl(al1, o+1);
      float a02 = __shfl(al0, o+2), a12 = __shfl(al1, o+2);
      float a03 = __shfl(al0, o+3), a13 = __shfl(al1, o+3);
      float w0 = head0 ? a00 : a10;
      float w1 = head0 ? a01 : a11;
      float w2 = head0 ? a02 : a12;
      float w3 = head0 ? a03 : a13;
      const float4* p0 = (const float4*)&h[(size_t)s_0*512 + dbase];
      const float4* p1 = (const float4*)&h[(size_t)s_1*512 + dbase];
      const float4* p2 = (const float4*)&h[(size_t)s_2*512 + dbase];
      const float4* p3 = (const float4*)&h[(size_t)s_3*512 + dbase];
      float4 u00 = p0[0], u01 = p0[1];
      float4 u10 = p1[0], u11 = p1[1];
      float4 u20 = p2[0], u21 = p2[1];
      float4 u30 = p3[0], u31 = p3[1];
      acc0[0] = fmaf(w0,u00.x,acc0[0]); acc0[1] = fmaf(w0,u00.y,acc0[1]);
      acc0[2] = fmaf(w0,u00.z,acc0[2]); acc0[3] = fmaf(w0,u00.w,acc0[3]);
      acc1[0] = fmaf(w0,u01.x,acc1[0]); acc1[1] = fmaf(w0,u01.y,acc1[1]);
      acc1[2] = fmaf(w0,u01.z,acc1[2]); acc1[3] = fmaf(w0,u01.w,acc1[3]);
      acc0[0] = fmaf(w1,u10.x,acc0[0]); acc0[1] = fmaf(w1,u10.y,acc0[1]);
      acc0[2] = fmaf(w1,u10.z,acc0[2]); acc0[3] = fmaf(w1,u10.w,acc0[3]);
      acc1[0] = fmaf(w1,u11.x,acc1[0]); acc1[1] = fmaf(w1,u11.y,acc1[1]);
      acc1[2] = fmaf(w1,u11.z,acc1[2]); acc1[3] = fmaf(w1,u11.w,acc1[3]);
      acc0[0] = fmaf(w2,u20.x,acc0[0]); acc0[1] = fmaf(w2,u20.y,acc0[1]);
      acc0[2] = fmaf(w2,u20.z,acc0[2]); acc0[3] = fmaf(w2,u20.w,acc0[3]);
      acc1[0] = fmaf(w2,u21.x,acc1[0]); acc1[1] = fmaf(w2,u21.y,acc1[1]);
      acc1[2] = fmaf(w2,u21.z,acc1[2]); acc1[3] = fmaf(w2,u21.w,acc1[3]);
      acc0[0] = fmaf(w3,u30.x,acc0[0]); acc0[1] = fmaf(w3,u30.y,acc0[1]);
      acc0[2] = fmaf(w3,u30.z,acc0[2]); acc0[3] = fmaf(w3,u30.w,acc0[3]);
      acc1[0] = fmaf(w3,u31.x,acc1[0]); acc1[1] = fmaf(w3,u31.y,acc1[1]);
      acc1[2] = fmaf(w3,u31.z,acc1[2]); acc1[3] = fmaf(w3,u31.w,acc1[3]);
    }
    for (; o < cc; ++o){
      int s = __shfl(sreg, o);
      float aA = __shfl(al0, o), aB = __shfl(al1, o);
      float w = head0 ? aA : aB;
      const float4* hp = (const float4*)&h[(size_t)s*512 + dbase];
      float4 v0 = hp[0], v1 = hp[1];
      acc0[0] = fmaf(w,v0.x,acc0[0]); acc0[1] = fmaf(w,v0.y,acc0[1]);
      acc0[2] = fmaf(w,v0.z,acc0[2]); acc0[3] = fmaf(w,v0.w,acc0[3]);
      acc1[0] = fmaf(w,v1.x,acc1[0]); acc1[1] = fmaf(w,v1.y,acc1[1]);
      acc1[2] = fmaf(w,v1.z,acc1[2]); acc1[3] = fmaf(w,v1.w,acc1[3]);
    }
  };

  if (cnt <= 64){
    int sreg = 0; float le0 = -1e30f, le1 = -1e30f;
    if (lane < cnt){
      sreg = ssrc[beg + lane];
      float2 a = *(const float2*)&asrc[2*sreg];
      le0 = leaky02(a.x + ad0); le1 = leaky02(a.y + ad1);
    }
    float m0 = wred_max(le0), m1 = wred_max(le1);
    float e0 = (lane < cnt) ? __expf(le0 - m0) : 0.f;
    float e1 = (lane < cnt) ? __expf(le1 - m1) : 0.f;
    float inv0 = 1.f / wred_sum(e0), inv1 = 1.f / wred_sum(e1);
    gather(sreg, e0*inv0, e1*inv1, cnt);
  } else {
    float m0 = -1e30f, m1 = -1e30f;
    for (int o = beg + lane; o < end; o += 64){
      int s = ssrc[o]; float2 a = *(const float2*)&asrc[2*s];
      m0 = fmaxf(m0, leaky02(a.x + ad0)); m1 = fmaxf(m1, leaky02(a.y + ad1));
    }
    m0 = wred_max(m0); m1 = wred_max(m1);
    float q0 = 0.f, q1 = 0.f;
    for (int o = beg + lane; o < end; o += 64){
      int s = ssrc[o]; float2 a = *(const float2*)&asrc[2*s];
      q0 += __expf(leaky02(a.x + ad0) - m0); q1 += __expf(leaky02(a.y + ad1) - m1);
    }
    float inv0 = 1.f / wred_sum(q0), inv1 = 1.f / wred_sum(q1);
    for (int c0 = beg; c0 < end; c0 += 64){
      int cc = end - c0; if (cc > 64) cc = 64;
      int sreg = 0; float al0 = 0.f, al1 = 0.f;
      if (lane < cc){
        sreg = ssrc[c0 + lane];
        float2 a = *(const float2*)&asrc[2*sreg];
        al0 = __expf(leaky02(a.x + ad0) - m0) * inv0;
        al1 = __expf(leaky02(a.y + ad1) - m1) * inv1;
      }
      gather(sreg, al0, al1, cc);
    }
  }

  // epilogue: +bias, relu, bf16 hi/lo split, fused column sum-of-squares
  float4 bi0 = *(const float4*)&bias[dbase];
  float4 bi1 = *(const float4*)&bias[dbase + 4];
  float o_[8];
  o_[0] = fmaxf(acc0[0] + bi0.x, 0.f); o_[1] = fmaxf(acc0[1] + bi0.y, 0.f);
  o_[2] = fmaxf(acc0[2] + bi0.z, 0.f); o_[3] = fmaxf(acc0[3] + bi0.w, 0.f);
  o_[4] = fmaxf(acc1[0] + bi1.x, 0.f); o_[5] = fmaxf(acc1[1] + bi1.y, 0.f);
  o_[6] = fmaxf(acc1[2] + bi1.z, 0.f); o_[7] = fmaxf(acc1[3] + bi1.w, 0.f);
  bf16x8 hv, lv;
  #pragma unroll
  for (int j = 0; j < 8; j++){
    __bf16 hh = (__bf16)o_[j]; hv[j] = hh; lv[j] = (__bf16)(o_[j] - (float)hh);
    sq[wid][dbase + j] = o_[j]*o_[j];
  }
  *(bf16x8*)&H[(size_t)d*512 + dbase] = hv;
  *(bf16x8*)&L[(size_t)d*512 + dbase] = lv;
  __syncthreads();
  int t = threadIdx.x;
  float s0 = sq[0][t] + sq[1][t] + sq[2][t] + sq[3][t];
  float s1 = sq[0][t+256] + sq[1][t+256] + sq[2][t+256] + sq[3][t+256];
  atomicAdd(&ssOut[t], s0);
  atomicAdd(&ssOut[t+256], s1);
}

// ---------- bias + LayerNorm + ReLU, wave per row; optional split + fused ss ----------
template<int C, bool SPLIT>
__global__ __launch_bounds__(256) void ln_relu_t(float* __restrict__ Z,
    const float* __restrict__ bias, const float* __restrict__ g,
    const float* __restrict__ bg, __bf16* __restrict__ H, __bf16* __restrict__ L,
    float* __restrict__ ssOut, int R){
  constexpr int VW = C / 64;
  __shared__ float sls[4][C];
  int lane = threadIdx.x & 63, wid = threadIdx.x >> 6;
  int r = blockIdx.x*4 + wid;
  size_t base = (size_t)r*C + lane*VW;
  float v[VW], bi[VW], gm[VW], bt[VW];
  if constexpr (VW == 4){
    float4 t0 = *(const float4*)&Z[base];
    float4 t1 = *(const float4*)&bias[lane*4];
    float4 t2 = *(const float4*)&g[lane*4];
    float4 t3 = *(const float4*)&bg[lane*4];
    v[0]=t0.x; v[1]=t0.y; v[2]=t0.z; v[3]=t0.w;
    bi[0]=t1.x; bi[1]=t1.y; bi[2]=t1.z; bi[3]=t1.w;
    gm[0]=t2.x; gm[1]=t2.y; gm[2]=t2.z; gm[3]=t2.w;
    bt[0]=t3.x; bt[1]=t3.y; bt[2]=t3.z; bt[3]=t3.w;
  } else if constexpr (VW == 2){
    float2 t0 = *(const float2*)&Z[base];
    float2 t1 = *(const float2*)&bias[lane*2];
    float2 t2 = *(const float2*)&g[lane*2];
    float2 t3 = *(const float2*)&bg[lane*2];
    v[0]=t0.x; v[1]=t0.y; bi[0]=t1.x; bi[1]=t1.y;
    gm[0]=t2.x; gm[1]=t2.y; bt[0]=t3.x; bt[1]=t3.y;
  } else {
    v[0] = Z[base]; bi[0] = bias[lane]; gm[0] = g[lane]; bt[0] = bg[lane];
  }
  float sum = 0.f;
  #pragma unroll
  for (int j = 0; j < VW; j++){ v[j] += bi[j]; sum += v[j]; }
  sum = wred_sum(sum);
  float mean = sum * (1.f/C);
  float sq = 0.f;
  #pragma unroll
  for (int j = 0; j < VW; j++){ float dz = v[j]-mean; sq += dz*dz; }
  sq = wred_sum(sq);
  float rs = 1.f / sqrtf(sq*(1.f/C) + 1e-5f);
  float o[VW];
  #pragma unroll
  for (int j = 0; j < VW; j++) o[j] = fmaxf((v[j]-mean)*rs*gm[j] + bt[j], 0.f);
  if constexpr (VW == 4) *(float4*)&Z[base] = make_float4(o[0],o[1],o[2],o[3]);
  else if constexpr (VW == 2) *(float2*)&Z[base] = make_float2(o[0],o[1]);
  else Z[base] = o[0];
  if constexpr (SPLIT){
    if constexpr (VW == 4){
      bf16x4 hv, lv;
      #pragma unroll
      for (int j = 0; j < 4; j++){ hv[j] = (__bf16)o[j]; lv[j] = (__bf16)(o[j]-(float)hv[j]); }
      *(bf16x4*)&H[base] = hv; *(bf16x4*)&L[base] = lv;
    } else if constexpr (VW == 2){
      bf16x2 hv, lv;
      #pragma unroll
      for (int j = 0; j < 2; j++){ hv[j] = (__bf16)o[j]; lv[j] = (__bf16)(o[j]-(float)hv[j]); }
      *(bf16x2*)&H[base] = hv; *(bf16x2*)&L[base] = lv;
    } else {
      __bf16 hv = (__bf16)o[0];
      H[base] = hv; L[base] = (__bf16)(o[0]-(float)hv);
    }
  }
  // fused column sum-of-squares of the LN output
  #pragma unroll
  for (int j = 0; j < VW; j++) sls[wid][lane*VW + j] = o[j]*o[j];
  __syncthreads();
  int t = threadIdx.x;
  if (t < C){
    float s = sls[0][t] + sls[1][t] + sls[2][t] + sls[3][t];
    atomicAdd(&ssOut[t], s);
  }
}

// ---------- final 64->3 GEMM with inline l2norm scale, packs (x,y,z,|h|^2) ----------
__global__ __launch_bounds__(256) void final_hf4(const float* __restrict__ A,
    const float* __restrict__ W3, const float* __restrict__ ss,
    const float* __restrict__ b3, float4* __restrict__ hf4, int N){
  __shared__ float w[64*3];
  __shared__ float b[3];
  if (threadIdx.x < 192){
    int k = threadIdx.x / 3;
    w[threadIdx.x] = W3[threadIdx.x] / fmaxf(sqrtf(ss[k]), 1e-12f);
  }
  if (threadIdx.x < 3) b[threadIdx.x] = b3[threadIdx.x];
  __syncthreads();
  int r = blockIdx.x*blockDim.x + threadIdx.x;
  if (r >= N) return;
  float x = b[0], y = b[1], z = b[2];
  #pragma unroll 8
  for (int k = 0; k < 64; ++k){
    float a = A[(size_t)r*64 + k];
    x = fmaf(a, w[k*3],   x);
    y = fmaf(a, w[k*3+1], y);
    z = fmaf(a, w[k*3+2], z);
  }
  float sq = x*x + y*y + z*z;
  hf4[r] = make_float4(x, y, z, sq);
}

// ---------- cdist: nontemporal float4 stores ----------
__global__ __launch_bounds__(256) void cdist_kernel(const float4* __restrict__ hf,
                                                    float* __restrict__ out, int N){
  int i = blockIdx.y;
  int j0 = (blockIdx.x*256 + threadIdx.x)*4;
  float4 a = hf[i];
  float4 b0 = hf[j0], b1 = hf[j0+1], b2 = hf[j0+2], b3 = hf[j0+3];
  f32x4 r; float d;
  d = a.w + b0.w - 2.f*(a.x*b0.x + a.y*b0.y + a.z*b0.z); r[0] = sqrtf(fmaxf(d, 0.f));
  d = a.w + b1.w - 2.f*(a.x*b1.x + a.y*b1.y + a.z*b1.z); r[1] = sqrtf(fmaxf(d, 0.f));
  d = a.w + b2.w - 2.f*(a.x*b2.x + a.y*b2.y + a.z*b2.z); r[2] = sqrtf(fmaxf(d, 0.f));
  d = a.w + b3.w - 2.f*(a.x*b3.x + a.y*b3.y + a.z*b3.z); r[3] = sqrtf(fmaxf(d, 0.f));
  __builtin_nontemporal_store(r, (f32x4*)&out[(size_t)i*N + j0]);
}

// ---------------------------------------------------------------------------
extern "C" void kernel_launch(void* const* d_in, const int* in_sizes, int n_in,
                              void* d_out, int out_size, void* d_ws, size_t ws_size,
                              hipStream_t stream){
  const int N = in_sizes[0] / 512;        // 16384
  const int E = in_sizes[1] / 2;          // 524288

  const float* x         = (const float*)d_in[0];
  const int*   ei        = (const int*)  d_in[1];
  const float* W         = (const float*)d_in[2];
  const float* att_src   = (const float*)d_in[3];
  const float* att_dst   = (const float*)d_in[4];
  const float* bias_conv = (const float*)d_in[5];
  const float* Wa  = (const float*)d_in[6];
  const float* ba  = (const float*)d_in[7];
  const float* ga  = (const float*)d_in[8];
  const float* bga = (const float*)d_in[9];
  const float* W1  = (const float*)d_in[10];
  const float* b1  = (const float*)d_in[11];
  const float* g1  = (const float*)d_in[12];
  const float* bg1 = (const float*)d_in[13];
  const float* W2  = (const float*)d_in[14];
  const float* b2  = (const float*)d_in[15];
  const float* g2  = (const float*)d_in[16];
  const float* bg2 = (const float*)d_in[17];
  const float* W3  = (const float*)d_in[18];
  const float* b3  = (const float*)d_in[19];

  const int* e_src = ei;
  const int* e_dst = ei + E;

  size_t off = 0;
  auto alloc = [&](size_t bytes)->char*{
    size_t o = off; off += (bytes + 255) & ~(size_t)255;
    return (char*)d_ws + o;
  };
  float* bufA  = (float*)alloc((size_t)N*512*4);
  float* bufB  = (float*)alloc((size_t)N*512*4);
  __bf16* Ah   = (__bf16*)alloc((size_t)N*512*2);
  __bf16* Al   = (__bf16*)alloc((size_t)N*512*2);
  __bf16* Bth  = (__bf16*)alloc(512*512*2);
  __bf16* Btl  = (__bf16*)alloc(512*512*2);
  // contiguous zero-init region: 5 ss buffers (512 f32 each) + deg (N ints)
  char* zbase  = alloc(5*512*4 + (size_t)N*4);
  float* ss1 = (float*)zbase;
  float* ss2 = ss1 + 512;
  float* ss3 = ss2 + 512;
  float* ss4 = ss3 + 512;
  float* ss5 = ss4 + 512;
  int*   deg = (int*)(ss5 + 512);
  float* asrc  = (float*)alloc((size_t)N*2*4);
  float* adst  = (float*)alloc((size_t)N*2*4);
  float4* hf4  = (float4*)alloc((size_t)N*16);
  int* offs    = (int*)alloc((size_t)(N+1)*4);
  int* cursor  = (int*)alloc((size_t)N*4);
  int* ssrc    = (int*)alloc((size_t)(E+N)*4);

  float* outF = (float*)d_out;

  hipMemsetAsync(zbase, 0, 5*512*4 + (size_t)N*4, stream);

  // ---- stage 1: l2norm(x) folded into W; h = x @ W' (split fused in staging) ----
  colnorm_sq<<<dim3(2,128), 256, 0, stream>>>(x, ss1, N, 512);
  split_tr_scaled<<<dim3(16,16), 256, 0, stream>>>(W, ss1, Bth, Btl, 512, 512);
  gemm_f32a_bf16x3<<<dim3(N/128, 8), 256, 0, stream>>>(x, Bth, Btl, bufA, N, 512, 512);

  // ---- GAT ----
  int nAttBlk = N/4;
  att_deg_kernel<<<nAttBlk + (E+255)/256, 256, 0, stream>>>(bufA, att_src, att_dst,
                                                            asrc, adst, e_dst, deg, nAttBlk, E);
  scan_kernel<<<1, 1024, 0, stream>>>(deg, offs, cursor, N);
  scatter_edges<<<(E+N+255)/256, 256, 0, stream>>>(e_src, e_dst, cursor, ssrc, E, N);
  gat_aggregate_w<<<N/4, 256, 0, stream>>>(bufA, offs, ssrc, asrc, adst, bias_conv,
                                           Ah, Al, ss2, N);

  // ---- stage 2: l2norm fold -> LN(gat_out @ Wa' + ba); ss3 fused into LN ----
  split_tr_scaled<<<dim3(8,16), 256, 0, stream>>>(Wa, ss2, Bth, Btl, 512, 256);
  gemm_bf16x3<<<dim3(N/128, 4), 256, 0, stream>>>(Ah, Al, Bth, Btl, bufB, N, 256, 512);
  ln_relu_t<256,true><<<N/4, 256, 0, stream>>>(bufB, ba, ga, bga, Ah, Al, ss3, N);

  // ---- stage 3 ----
  split_tr_scaled<<<dim3(4,8), 256, 0, stream>>>(W1, ss3, Bth, Btl, 256, 128);
  gemm_bf16x3<<<dim3(N/128, 2), 256, 0, stream>>>(Ah, Al, Bth, Btl, bufA, N, 128, 256);
  ln_relu_t<128,true><<<N/4, 256, 0, stream>>>(bufA, b1, g1, bg1, Ah, Al, ss4, N);

  // ---- stage 4 ----
  split_tr_scaled<<<dim3(2,4), 256, 0, stream>>>(W2, ss4, Bth, Btl, 128, 64);
  gemm_bf16x3<<<dim3(N/128, 1), 256, 0, stream>>>(Ah, Al, Bth, Btl, bufB, N, 64, 128);
  ln_relu_t<64,false><<<N/4, 256, 0, stream>>>(bufB, b2, g2, bg2,
                                               (__bf16*)nullptr, (__bf16*)nullptr, ss5, N);

  // ---- stage 5: final projection (scale inline) + cdist ----
  final_hf4<<<(N+255)/256, 256, 0, stream>>>(bufB, W3, ss5, b3, hf4, N);
  cdist_kernel<<<dim3(N/1024, N), 256, 0, stream>>>(hf4, outF, N);
}

// Round 9
// 766.599 us; speedup vs baseline: 1.2104x; 1.2104x over previous
//
#include <hip/hip_runtime.h>
#include <math.h>

// ---------------------------------------------------------------------------
// GATNet pipeline, MI355X round 8: exact round-5 base (761.7us proven) + ONE
// change: stage 4 (split_tr + 128-block GEMM + ln64) fused into a single
// wave-per-row f32 kernel (gemm64_ln).
// ---------------------------------------------------------------------------

typedef __bf16 bf16x8 __attribute__((ext_vector_type(8)));
typedef __bf16 bf16x4 __attribute__((ext_vector_type(4)));
typedef __bf16 bf16x2 __attribute__((ext_vector_type(2)));
typedef float  f32x4  __attribute__((ext_vector_type(4)));
typedef short  short8 __attribute__((ext_vector_type(8)));

static __device__ __forceinline__ float leaky02(float e){ return e >= 0.f ? e : 0.2f*e; }

static __device__ __forceinline__ float wred_sum(float v){
  #pragma unroll
  for (int m = 1; m < 64; m <<= 1) v += __shfl_xor(v, m);
  return v;
}
static __device__ __forceinline__ float wred_max(float v){
  #pragma unroll
  for (int m = 1; m < 64; m <<= 1) v = fmaxf(v, __shfl_xor(v, m));
  return v;
}

// ---------- column sum-of-squares, f32 input ----------
__global__ void colnorm_sq(const float* __restrict__ X, float* __restrict__ ss, int R, int C){
  int c = blockIdx.x*blockDim.x + threadIdx.x;
  if (c >= C) return;
  int r0 = blockIdx.y * 128;
  int r1 = r0 + 128; if (r1 > R) r1 = R;
  float s = 0.f;
  for (int r = r0; r < r1; ++r){ float v = X[(size_t)r*C + c]; s = fmaf(v, v, s); }
  atomicAdd(&ss[c], s);
}

// ---------- column sum-of-squares from bf16 hi/lo pair ----------
__global__ void colnorm_sq_hl(const __bf16* __restrict__ H, const __bf16* __restrict__ L,
                              float* __restrict__ ss, int R, int C){
  int c = blockIdx.x*blockDim.x + threadIdx.x;
  if (c >= C) return;
  int r0 = blockIdx.y * 128;
  int r1 = r0 + 128; if (r1 > R) r1 = R;
  float s = 0.f;
  for (int r = r0; r < r1; ++r){
    float v = (float)H[(size_t)r*C + c] + (float)L[(size_t)r*C + c];
    s = fmaf(v, v, s);
  }
  atomicAdd(&ss[c], s);
}

// ---------- l2norm-scale + split + transpose: W[K][N] -> TH/TL [N][K] bf16 ----------
__global__ __launch_bounds__(256) void split_tr_scaled(const float* __restrict__ B,
    const float* __restrict__ ss,
    __bf16* __restrict__ TH, __bf16* __restrict__ TL, int K, int N){
  __shared__ float tile[32][33];
  int lx = threadIdx.x & 31, ly = threadIdx.x >> 5;
  int kb = blockIdx.y*32, nb = blockIdx.x*32;
  #pragma unroll
  for (int i = 0; i < 4; i++){
    int kr = kb + ly + i*8;
    float inv = 1.f / fmaxf(sqrtf(ss[kr]), 1e-12f);
    tile[ly + i*8][lx] = B[(size_t)kr*N + nb + lx] * inv;
  }
  __syncthreads();
  #pragma unroll
  for (int i = 0; i < 4; i++){
    int nl = ly + i*8;
    float v = tile[lx][nl];
    __bf16 h = (__bf16)v;
    TH[(size_t)(nb + nl)*K + kb + lx] = h;
    TL[(size_t)(nb + nl)*K + kb + lx] = (__bf16)(v - (float)h);
  }
}

// ---------- split-bf16 MFMA GEMM, A pre-split bf16 (3-term) ----------
__global__ __launch_bounds__(256) void gemm_bf16x3(
    const __bf16* __restrict__ Ah, const __bf16* __restrict__ Al,
    const __bf16* __restrict__ Bth, const __bf16* __restrict__ Btl,
    float* __restrict__ C, int M, int N, int K)
{
  __shared__ __align__(16) __bf16 sAh[128][40];
  __shared__ __align__(16) __bf16 sAl[128][40];
  __shared__ __align__(16) __bf16 sBh[64][40];
  __shared__ __align__(16) __bf16 sBl[64][40];
  int tid = threadIdx.x;
  int lane = tid & 63, wave = tid >> 6;
  int wr = wave >> 1, wc = wave & 1;
  int rowBase = blockIdx.x << 7, colBase = blockIdx.y << 6;

  int ar = tid >> 2;
  int ac = tid & 3;

  short8 rAh0, rAh1, rAl0, rAl1, rBh, rBl;
  auto loadA = [&](int k0){
    rAh0 = *(const short8*)(Ah + (size_t)(rowBase + ar     )*K + k0 + ac*8);
    rAh1 = *(const short8*)(Ah + (size_t)(rowBase + ar + 64)*K + k0 + ac*8);
    rAl0 = *(const short8*)(Al + (size_t)(rowBase + ar     )*K + k0 + ac*8);
    rAl1 = *(const short8*)(Al + (size_t)(rowBase + ar + 64)*K + k0 + ac*8);
    rBh  = *(const short8*)(Bth + (size_t)(colBase + ar)*K + k0 + ac*8);
    rBl  = *(const short8*)(Btl + (size_t)(colBase + ar)*K + k0 + ac*8);
  };

  f32x4 acc[4][2];
  #pragma unroll
  for (int m = 0; m < 4; m++)
    #pragma unroll
    for (int n = 0; n < 2; n++) acc[m][n] = (f32x4){0.f,0.f,0.f,0.f};

  loadA(0);
  int nsteps = K >> 5;
  for (int s = 0; s < nsteps; ++s){
    __syncthreads();
    *(short8*)&sAh[ar][ac*8]      = rAh0;
    *(short8*)&sAh[ar+64][ac*8]   = rAh1;
    *(short8*)&sAl[ar][ac*8]      = rAl0;
    *(short8*)&sAl[ar+64][ac*8]   = rAl1;
    *(short8*)&sBh[ar][ac*8]      = rBh;
    *(short8*)&sBl[ar][ac*8]      = rBl;
    if (s + 1 < nsteps) loadA((s+1) << 5);
    __syncthreads();

    int kslot = lane >> 4;
    bf16x8 fah[4], fal[4], fbh[2], fbl[2];
    #pragma unroll
    for (int m = 0; m < 4; m++){
      int r = wr*64 + m*16 + (lane & 15);
      fah[m] = *(const bf16x8*)&sAh[r][kslot*8];
      fal[m] = *(const bf16x8*)&sAl[r][kslot*8];
    }
    #pragma unroll
    for (int n = 0; n < 2; n++){
      int c = wc*32 + n*16 + (lane & 15);
      fbh[n] = *(const bf16x8*)&sBh[c][kslot*8];
      fbl[n] = *(const bf16x8*)&sBl[c][kslot*8];
    }
    #pragma unroll
    for (int m = 0; m < 4; m++)
      #pragma unroll
      for (int n = 0; n < 2; n++){
        acc[m][n] = __builtin_amdgcn_mfma_f32_16x16x32_bf16(fah[m], fbh[n], acc[m][n], 0,0,0);
        acc[m][n] = __builtin_amdgcn_mfma_f32_16x16x32_bf16(fah[m], fbl[n], acc[m][n], 0,0,0);
        acc[m][n] = __builtin_amdgcn_mfma_f32_16x16x32_bf16(fal[m], fbh[n], acc[m][n], 0,0,0);
      }
  }

  int rg = lane >> 4, cl = lane & 15;
  #pragma unroll
  for (int m = 0; m < 4; m++)
    #pragma unroll
    for (int n = 0; n < 2; n++)
      #pragma unroll
      for (int j = 0; j < 4; j++)
        C[(size_t)(rowBase + wr*64 + m*16 + rg*4 + j)*N + colBase + wc*32 + n*16 + cl] = acc[m][n][j];
}

// ---------- same GEMM but A is f32 (stage 1: reads x directly, splits in-reg) ----------
__global__ __launch_bounds__(256) void gemm_f32a_bf16x3(
    const float* __restrict__ A,
    const __bf16* __restrict__ Bth, const __bf16* __restrict__ Btl,
    float* __restrict__ C, int M, int N, int K)
{
  __shared__ __align__(16) __bf16 sAh[128][40];
  __shared__ __align__(16) __bf16 sAl[128][40];
  __shared__ __align__(16) __bf16 sBh[64][40];
  __shared__ __align__(16) __bf16 sBl[64][40];
  int tid = threadIdx.x;
  int lane = tid & 63, wave = tid >> 6;
  int wr = wave >> 1, wc = wave & 1;
  int rowBase = blockIdx.x << 7, colBase = blockIdx.y << 6;

  int ar = tid >> 2;
  int ac = tid & 3;

  float4 rA0a, rA0b, rA1a, rA1b; short8 rBh, rBl;
  auto loadA = [&](int k0){
    const float* p0 = A + (size_t)(rowBase + ar)*K + k0 + ac*8;
    rA0a = *(const float4*)p0; rA0b = *(const float4*)(p0 + 4);
    const float* p1 = A + (size_t)(rowBase + ar + 64)*K + k0 + ac*8;
    rA1a = *(const float4*)p1; rA1b = *(const float4*)(p1 + 4);
    rBh  = *(const short8*)(Bth + (size_t)(colBase + ar)*K + k0 + ac*8);
    rBl  = *(const short8*)(Btl + (size_t)(colBase + ar)*K + k0 + ac*8);
  };
  auto splitst = [&](float4 a, float4 b, __bf16* dh, __bf16* dl){
    float t[8] = {a.x,a.y,a.z,a.w,b.x,b.y,b.z,b.w};
    bf16x8 hv, lv;
    #pragma unroll
    for (int j = 0; j < 8; j++){
      __bf16 h = (__bf16)t[j]; hv[j] = h; lv[j] = (__bf16)(t[j] - (float)h);
    }
    *(bf16x8*)dh = hv; *(bf16x8*)dl = lv;
  };

  f32x4 acc[4][2];
  #pragma unroll
  for (int m = 0; m < 4; m++)
    #pragma unroll
    for (int n = 0; n < 2; n++) acc[m][n] = (f32x4){0.f,0.f,0.f,0.f};

  loadA(0);
  int nsteps = K >> 5;
  for (int s = 0; s < nsteps; ++s){
    __syncthreads();
    splitst(rA0a, rA0b, &sAh[ar][ac*8],    &sAl[ar][ac*8]);
    splitst(rA1a, rA1b, &sAh[ar+64][ac*8], &sAl[ar+64][ac*8]);
    *(short8*)&sBh[ar][ac*8] = rBh;
    *(short8*)&sBl[ar][ac*8] = rBl;
    if (s + 1 < nsteps) loadA((s+1) << 5);
    __syncthreads();

    int kslot = lane >> 4;
    bf16x8 fah[4], fal[4], fbh[2], fbl[2];
    #pragma unroll
    for (int m = 0; m < 4; m++){
      int r = wr*64 + m*16 + (lane & 15);
      fah[m] = *(const bf16x8*)&sAh[r][kslot*8];
      fal[m] = *(const bf16x8*)&sAl[r][kslot*8];
    }
    #pragma unroll
    for (int n = 0; n < 2; n++){
      int c = wc*32 + n*16 + (lane & 15);
      fbh[n] = *(const bf16x8*)&sBh[c][kslot*8];
      fbl[n] = *(const bf16x8*)&sBl[c][kslot*8];
    }
    #pragma unroll
    for (int m = 0; m < 4; m++)
      #pragma unroll
      for (int n = 0; n < 2; n++){
        acc[m][n] = __builtin_amdgcn_mfma_f32_16x16x32_bf16(fah[m], fbh[n], acc[m][n], 0,0,0);
        acc[m][n] = __builtin_amdgcn_mfma_f32_16x16x32_bf16(fah[m], fbl[n], acc[m][n], 0,0,0);
        acc[m][n] = __builtin_amdgcn_mfma_f32_16x16x32_bf16(fal[m], fbh[n], acc[m][n], 0,0,0);
      }
  }

  int rg = lane >> 4, cl = lane & 15;
  #pragma unroll
  for (int m = 0; m < 4; m++)
    #pragma unroll
    for (int n = 0; n < 2; n++)
      #pragma unroll
      for (int j = 0; j < 4; j++)
        C[(size_t)(rowBase + wr*64 + m*16 + rg*4 + j)*N + colBase + wc*32 + n*16 + cl] = acc[m][n][j];
}

// ---------- GAT attention coefficients: one wave per node ----------
__global__ __launch_bounds__(256) void att_kernel(const float* __restrict__ h,
    const float* __restrict__ att_src, const float* __restrict__ att_dst,
    float* __restrict__ asrc, float* __restrict__ adst, int N){
  int lane = threadIdx.x & 63;
  int node = blockIdx.x*4 + (threadIdx.x >> 6);
  const float4* hp = (const float4*)(h + (size_t)node*512);
  float4 v0 = hp[lane], v1 = hp[64 + lane];
  float4 as0 = ((const float4*)att_src)[lane], as1 = ((const float4*)att_src)[64+lane];
  float4 ad0 = ((const float4*)att_dst)[lane], ad1 = ((const float4*)att_dst)[64+lane];
  float s0 = v0.x*as0.x + v0.y*as0.y + v0.z*as0.z + v0.w*as0.w;
  float s1 = v1.x*as1.x + v1.y*as1.y + v1.z*as1.z + v1.w*as1.w;
  float d0 = v0.x*ad0.x + v0.y*ad0.y + v0.z*ad0.z + v0.w*ad0.w;
  float d1 = v1.x*ad1.x + v1.y*ad1.y + v1.z*ad1.z + v1.w*ad1.w;
  s0 = wred_sum(s0); s1 = wred_sum(s1); d0 = wred_sum(d0); d1 = wred_sum(d1);
  if (lane == 0){
    asrc[2*node] = s0; asrc[2*node+1] = s1;
    adst[2*node] = d0; adst[2*node+1] = d1;
  }
}

// ---------- CSR build ----------
__global__ void deg_count(const int* __restrict__ dst, int* deg, int E){
  int e = blockIdx.x*blockDim.x + threadIdx.x;
  if (e < E) atomicAdd(&deg[dst[e]], 1);
}
__global__ __launch_bounds__(1024) void scan_kernel(const int* __restrict__ deg,
    int* __restrict__ offs, int* __restrict__ cursor, int n){
  __shared__ int part[1024];
  int t = threadIdx.x;
  int chunk = (n + 1023) >> 10;
  int base = t * chunk;
  int loc[32];
  int local = 0;
  for (int k = 0; k < chunk; k++){
    int idx = base + k; loc[k] = local;
    if (idx < n) local += deg[idx] + 1;       // +1 self-loop
  }
  part[t] = local; __syncthreads();
  for (int off = 1; off < 1024; off <<= 1){
    int v = (t >= off) ? part[t-off] : 0; __syncthreads();
    part[t] += v; __syncthreads();
  }
  int excl = part[t] - local;
  for (int k = 0; k < chunk; k++){
    int idx = base + k;
    if (idx < n){ int o = excl + loc[k]; offs[idx] = o; cursor[idx] = o; }
  }
  if (t == 1023) offs[n] = part[1023];
}
__global__ void scatter_edges(const int* __restrict__ src, const int* __restrict__ dst,
                              int* cursor, int* __restrict__ ssrc, int E, int N){
  int e = blockIdx.x*blockDim.x + threadIdx.x;
  if (e < E){
    int d = dst[e]; int pos = atomicAdd(&cursor[d], 1); ssrc[pos] = src[e];
  } else if (e < E + N){
    int i = e - E; int pos = atomicAdd(&cursor[i], 1); ssrc[pos] = i;
  }
}

// ---------- GAT aggregation: ONE WAVE per dst node (round-5 proven form) ----------
__global__ __launch_bounds__(256) void gat_aggregate_w(const float* __restrict__ h,
    const int* __restrict__ offs, const int* __restrict__ ssrc,
    const float* __restrict__ asrc, const float* __restrict__ adst,
    const float* __restrict__ bias,
    __bf16* __restrict__ H, __bf16* __restrict__ L, int N){
  int lane = threadIdx.x & 63;
  int d = blockIdx.x*4 + (threadIdx.x >> 6);
  int beg = offs[d], end = offs[d+1], cnt = end - beg;
  float ad0 = adst[2*d], ad1 = adst[2*d+1];

  int dbase = lane*8;                 // this lane owns dims dbase..dbase+7
  bool head0 = dbase < 256;
  f32x4 acc0 = {0.f,0.f,0.f,0.f}, acc1 = {0.f,0.f,0.f,0.f};

  if (cnt <= 64){
    int sreg = 0; float le0 = -1e30f, le1 = -1e30f;
    if (lane < cnt){
      sreg = ssrc[beg + lane];
      float2 a = *(const float2*)&asrc[2*sreg];
      le0 = leaky02(a.x + ad0); le1 = leaky02(a.y + ad1);
    }
    float m0 = wred_max(le0), m1 = wred_max(le1);
    float e0 = (lane < cnt) ? __expf(le0 - m0) : 0.f;
    float e1 = (lane < cnt) ? __expf(le1 - m1) : 0.f;
    float inv0 = 1.f / wred_sum(e0), inv1 = 1.f / wred_sum(e1);
    float al0 = e0*inv0, al1 = e1*inv1;
    for (int o = 0; o < cnt; ++o){
      int s = __shfl(sreg, o);
      float aA = __shfl(al0, o), aB = __shfl(al1, o);
      float al = head0 ? aA : aB;
      const float4* hp = (const float4*)&h[(size_t)s*512 + dbase];
      float4 v0 = hp[0], v1 = hp[1];
      acc0[0] = fmaf(al, v0.x, acc0[0]); acc0[1] = fmaf(al, v0.y, acc0[1]);
      acc0[2] = fmaf(al, v0.z, acc0[2]); acc0[3] = fmaf(al, v0.w, acc0[3]);
      acc1[0] = fmaf(al, v1.x, acc1[0]); acc1[1] = fmaf(al, v1.y, acc1[1]);
      acc1[2] = fmaf(al, v1.z, acc1[2]); acc1[3] = fmaf(al, v1.w, acc1[3]);
    }
  } else {
    float m0 = -1e30f, m1 = -1e30f;
    for (int o = beg + lane; o < end; o += 64){
      int s = ssrc[o]; float2 a = *(const float2*)&asrc[2*s];
      m0 = fmaxf(m0, leaky02(a.x + ad0)); m1 = fmaxf(m1, leaky02(a.y + ad1));
    }
    m0 = wred_max(m0); m1 = wred_max(m1);
    float q0 = 0.f, q1 = 0.f;
    for (int o = beg + lane; o < end; o += 64){
      int s = ssrc[o]; float2 a = *(const float2*)&asrc[2*s];
      q0 += __expf(leaky02(a.x + ad0) - m0); q1 += __expf(leaky02(a.y + ad1) - m1);
    }
    float inv0 = 1.f / wred_sum(q0), inv1 = 1.f / wred_sum(q1);
    for (int c0 = beg; c0 < end; c0 += 64){
      int cc = end - c0; if (cc > 64) cc = 64;
      int sreg = 0; float al0 = 0.f, al1 = 0.f;
      if (lane < cc){
        sreg = ssrc[c0 + lane];
        float2 a = *(const float2*)&asrc[2*sreg];
        al0 = __expf(leaky02(a.x + ad0) - m0) * inv0;
        al1 = __expf(leaky02(a.y + ad1) - m1) * inv1;
      }
      for (int o = 0; o < cc; ++o){
        int s = __shfl(sreg, o);
        float aA = __shfl(al0, o), aB = __shfl(al1, o);
        float al = head0 ? aA : aB;
        const float4* hp = (const float4*)&h[(size_t)s*512 + dbase];
        float4 v0 = hp[0], v1 = hp[1];
        acc0[0] = fmaf(al, v0.x, acc0[0]); acc0[1] = fmaf(al, v0.y, acc0[1]);
        acc0[2] = fmaf(al, v0.z, acc0[2]); acc0[3] = fmaf(al, v0.w, acc0[3]);
        acc1[0] = fmaf(al, v1.x, acc1[0]); acc1[1] = fmaf(al, v1.y, acc1[1]);
        acc1[2] = fmaf(al, v1.z, acc1[2]); acc1[3] = fmaf(al, v1.w, acc1[3]);
      }
    }
  }

  // epilogue: +bias, relu, bf16 hi/lo split, 16B stores
  float4 bi0 = *(const float4*)&bias[dbase];
  float4 bi1 = *(const float4*)&bias[dbase + 4];
  float o_[8];
  o_[0] = fmaxf(acc0[0] + bi0.x, 0.f); o_[1] = fmaxf(acc0[1] + bi0.y, 0.f);
  o_[2] = fmaxf(acc0[2] + bi0.z, 0.f); o_[3] = fmaxf(acc0[3] + bi0.w, 0.f);
  o_[4] = fmaxf(acc1[0] + bi1.x, 0.f); o_[5] = fmaxf(acc1[1] + bi1.y, 0.f);
  o_[6] = fmaxf(acc1[2] + bi1.z, 0.f); o_[7] = fmaxf(acc1[3] + bi1.w, 0.f);
  bf16x8 hv, lv;
  #pragma unroll
  for (int j = 0; j < 8; j++){
    __bf16 hh = (__bf16)o_[j]; hv[j] = hh; lv[j] = (__bf16)(o_[j] - (float)hh);
  }
  *(bf16x8*)&H[(size_t)d*512 + dbase] = hv;
  *(bf16x8*)&L[(size_t)d*512 + dbase] = lv;
}

// ---------- bias + LayerNorm + ReLU, wave per row, optional bf16 split ----------
template<int C, bool SPLIT>
__global__ __launch_bounds__(256) void ln_relu_t(float* __restrict__ Z,
    const float* __restrict__ bias, const float* __restrict__ g,
    const float* __restrict__ bg, __bf16* __restrict__ H, __bf16* __restrict__ L, int R){
  constexpr int VW = C / 64;
  int lane = threadIdx.x & 63, wid = threadIdx.x >> 6;
  int r = blockIdx.x*4 + wid;
  size_t base = (size_t)r*C + lane*VW;
  float v[VW], bi[VW], gm[VW], bt[VW];
  if constexpr (VW == 4){
    float4 t0 = *(const float4*)&Z[base];
    float4 t1 = *(const float4*)&bias[lane*4];
    float4 t2 = *(const float4*)&g[lane*4];
    float4 t3 = *(const float4*)&bg[lane*4];
    v[0]=t0.x; v[1]=t0.y; v[2]=t0.z; v[3]=t0.w;
    bi[0]=t1.x; bi[1]=t1.y; bi[2]=t1.z; bi[3]=t1.w;
    gm[0]=t2.x; gm[1]=t2.y; gm[2]=t2.z; gm[3]=t2.w;
    bt[0]=t3.x; bt[1]=t3.y; bt[2]=t3.z; bt[3]=t3.w;
  } else if constexpr (VW == 2){
    float2 t0 = *(const float2*)&Z[base];
    float2 t1 = *(const float2*)&bias[lane*2];
    float2 t2 = *(const float2*)&g[lane*2];
    float2 t3 = *(const float2*)&bg[lane*2];
    v[0]=t0.x; v[1]=t0.y; bi[0]=t1.x; bi[1]=t1.y;
    gm[0]=t2.x; gm[1]=t2.y; bt[0]=t3.x; bt[1]=t3.y;
  } else {
    v[0] = Z[base]; bi[0] = bias[lane]; gm[0] = g[lane]; bt[0] = bg[lane];
  }
  float sum = 0.f;
  #pragma unroll
  for (int j = 0; j < VW; j++){ v[j] += bi[j]; sum += v[j]; }
  sum = wred_sum(sum);
  float mean = sum * (1.f/C);
  float sq = 0.f;
  #pragma unroll
  for (int j = 0; j < VW; j++){ float dz = v[j]-mean; sq += dz*dz; }
  sq = wred_sum(sq);
  float rs = 1.f / sqrtf(sq*(1.f/C) + 1e-5f);
  float o[VW];
  #pragma unroll
  for (int j = 0; j < VW; j++) o[j] = fmaxf((v[j]-mean)*rs*gm[j] + bt[j], 0.f);
  if constexpr (VW == 4) *(float4*)&Z[base] = make_float4(o[0],o[1],o[2],o[3]);
  else if constexpr (VW == 2) *(float2*)&Z[base] = make_float2(o[0],o[1]);
  else Z[base] = o[0];
  if constexpr (SPLIT){
    if constexpr (VW == 4){
      bf16x4 hv, lv;
      #pragma unroll
      for (int j = 0; j < 4; j++){ hv[j] = (__bf16)o[j]; lv[j] = (__bf16)(o[j]-(float)hv[j]); }
      *(bf16x4*)&H[base] = hv; *(bf16x4*)&L[base] = lv;
    } else if constexpr (VW == 2){
      bf16x2 hv, lv;
      #pragma unroll
      for (int j = 0; j < 2; j++){ hv[j] = (__bf16)o[j]; lv[j] = (__bf16)(o[j]-(float)hv[j]); }
      *(bf16x2*)&H[base] = hv; *(bf16x2*)&L[base] = lv;
    } else {
      __bf16 hv = (__bf16)o[0];
      H[base] = hv; L[base] = (__bf16)(o[0]-(float)hv);
    }
  }
}

// ---------- FUSED stage 4: wave per row, W2 l2norm-scaled in LDS, f32 math ----------
// out_row = relu(LN(row @ W2scaled + b2)); lane owns one of the 64 output cols.
__global__ __launch_bounds__(256) void gemm64_ln(const float* __restrict__ A,
    const float* __restrict__ W2, const float* __restrict__ ss,
    const float* __restrict__ b2, const float* __restrict__ g2,
    const float* __restrict__ bg2, float* __restrict__ Zout, int N){
  __shared__ float w2s[128*64];
  __shared__ float invs[128];
  __shared__ float rowbuf[4][128];
  int t = threadIdx.x;
  int lane = t & 63, wid = t >> 6;
  if (t < 128) invs[t] = 1.f / fmaxf(sqrtf(ss[t]), 1e-12f);
  __syncthreads();
  #pragma unroll
  for (int i = 0; i < 32; i++){
    int idx = t + i*256;
    w2s[idx] = W2[idx] * invs[idx >> 6];
  }
  int r = blockIdx.x*4 + wid;
  float2 rv = *(const float2*)&A[(size_t)r*128 + lane*2];
  rowbuf[wid][lane*2]   = rv.x;
  rowbuf[wid][lane*2+1] = rv.y;
  __syncthreads();
  float acc = b2[lane];
  #pragma unroll 8
  for (int k = 0; k < 128; ++k)
    acc = fmaf(rowbuf[wid][k], w2s[k*64 + lane], acc);
  // LayerNorm across 64 lanes (one element per lane)
  float mean = wred_sum(acc) * (1.f/64.f);
  float dz = acc - mean;
  float var = wred_sum(dz*dz) * (1.f/64.f);
  float rs = 1.f / sqrtf(var + 1e-5f);
  float o = fmaxf(dz*rs*g2[lane] + bg2[lane], 0.f);
  Zout[(size_t)r*64 + lane] = o;
}

// ---------- final 64->3 GEMM with inline l2norm scale, packs (x,y,z,|h|^2) ----------
__global__ __launch_bounds__(256) void final_hf4(const float* __restrict__ A,
    const float* __restrict__ W3, const float* __restrict__ ss,
    const float* __restrict__ b3, float4* __restrict__ hf4, int N){
  __shared__ float w[64*3];
  __shared__ float b[3];
  if (threadIdx.x < 192){
    int k = threadIdx.x / 3;
    w[threadIdx.x] = W3[threadIdx.x] / fmaxf(sqrtf(ss[k]), 1e-12f);
  }
  if (threadIdx.x < 3) b[threadIdx.x] = b3[threadIdx.x];
  __syncthreads();
  int r = blockIdx.x*blockDim.x + threadIdx.x;
  if (r >= N) return;
  float x = b[0], y = b[1], z = b[2];
  #pragma unroll 8
  for (int k = 0; k < 64; ++k){
    float a = A[(size_t)r*64 + k];
    x = fmaf(a, w[k*3],   x);
    y = fmaf(a, w[k*3+1], y);
    z = fmaf(a, w[k*3+2], z);
  }
  float sq = x*x + y*y + z*z;
  hf4[r] = make_float4(x, y, z, sq);
}

// ---------- cdist: nontemporal float4 stores ----------
__global__ __launch_bounds__(256) void cdist_kernel(const float4* __restrict__ hf,
                                                    float* __restrict__ out, int N){
  int i = blockIdx.y;
  int j0 = (blockIdx.x*256 + threadIdx.x)*4;
  float4 a = hf[i];
  float4 b0 = hf[j0], b1 = hf[j0+1], b2 = hf[j0+2], b3 = hf[j0+3];
  f32x4 r; float d;
  d = a.w + b0.w - 2.f*(a.x*b0.x + a.y*b0.y + a.z*b0.z); r[0] = sqrtf(fmaxf(d, 0.f));
  d = a.w + b1.w - 2.f*(a.x*b1.x + a.y*b1.y + a.z*b1.z); r[1] = sqrtf(fmaxf(d, 0.f));
  d = a.w + b2.w - 2.f*(a.x*b2.x + a.y*b2.y + a.z*b2.z); r[2] = sqrtf(fmaxf(d, 0.f));
  d = a.w + b3.w - 2.f*(a.x*b3.x + a.y*b3.y + a.z*b3.z); r[3] = sqrtf(fmaxf(d, 0.f));
  __builtin_nontemporal_store(r, (f32x4*)&out[(size_t)i*N + j0]);
}

// ---------------------------------------------------------------------------
extern "C" void kernel_launch(void* const* d_in, const int* in_sizes, int n_in,
                              void* d_out, int out_size, void* d_ws, size_t ws_size,
                              hipStream_t stream){
  const int N = in_sizes[0] / 512;        // 16384
  const int E = in_sizes[1] / 2;          // 524288

  const float* x         = (const float*)d_in[0];
  const int*   ei        = (const int*)  d_in[1];
  const float* W         = (const float*)d_in[2];
  const float* att_src   = (const float*)d_in[3];
  const float* att_dst   = (const float*)d_in[4];
  const float* bias_conv = (const float*)d_in[5];
  const float* Wa  = (const float*)d_in[6];
  const float* ba  = (const float*)d_in[7];
  const float* ga  = (const float*)d_in[8];
  const float* bga = (const float*)d_in[9];
  const float* W1  = (const float*)d_in[10];
  const float* b1  = (const float*)d_in[11];
  const float* g1  = (const float*)d_in[12];
  const float* bg1 = (const float*)d_in[13];
  const float* W2  = (const float*)d_in[14];
  const float* b2  = (const float*)d_in[15];
  const float* g2  = (const float*)d_in[16];
  const float* bg2 = (const float*)d_in[17];
  const float* W3  = (const float*)d_in[18];
  const float* b3  = (const float*)d_in[19];

  const int* e_src = ei;
  const int* e_dst = ei + E;

  size_t off = 0;
  auto alloc = [&](size_t bytes)->char*{
    size_t o = off; off += (bytes + 255) & ~(size_t)255;
    return (char*)d_ws + o;
  };
  float* bufA  = (float*)alloc((size_t)N*512*4);
  float* bufB  = (float*)alloc((size_t)N*512*4);
  __bf16* Ah   = (__bf16*)alloc((size_t)N*512*2);
  __bf16* Al   = (__bf16*)alloc((size_t)N*512*2);
  __bf16* Bth  = (__bf16*)alloc(512*512*2);
  __bf16* Btl  = (__bf16*)alloc(512*512*2);
  // contiguous zero-init region: 5 ss buffers (512 f32 each) + deg (N ints)
  char* zbase  = alloc(5*512*4 + (size_t)N*4);
  float* ss1 = (float*)zbase;
  float* ss2 = ss1 + 512;
  float* ss3 = ss2 + 512;
  float* ss4 = ss3 + 512;
  float* ss5 = ss4 + 512;
  int*   deg = (int*)(ss5 + 512);
  float* asrc  = (float*)alloc((size_t)N*2*4);
  float* adst  = (float*)alloc((size_t)N*2*4);
  float4* hf4  = (float4*)alloc((size_t)N*16);
  int* offs    = (int*)alloc((size_t)(N+1)*4);
  int* cursor  = (int*)alloc((size_t)N*4);
  int* ssrc    = (int*)alloc((size_t)(E+N)*4);

  float* outF = (float*)d_out;

  hipMemsetAsync(zbase, 0, 5*512*4 + (size_t)N*4, stream);

  // ---- stage 1: l2norm(x) folded into W; h = x @ W' (split fused in staging) ----
  colnorm_sq<<<dim3(2,128), 256, 0, stream>>>(x, ss1, N, 512);
  split_tr_scaled<<<dim3(16,16), 256, 0, stream>>>(W, ss1, Bth, Btl, 512, 512);
  gemm_f32a_bf16x3<<<dim3(N/128, 8), 256, 0, stream>>>(x, Bth, Btl, bufA, N, 512, 512);

  // ---- GAT ----
  att_kernel<<<N/4, 256, 0, stream>>>(bufA, att_src, att_dst, asrc, adst, N);
  deg_count<<<(E+255)/256, 256, 0, stream>>>(e_dst, deg, E);
  scan_kernel<<<1, 1024, 0, stream>>>(deg, offs, cursor, N);
  scatter_edges<<<(E+N+255)/256, 256, 0, stream>>>(e_src, e_dst, cursor, ssrc, E, N);
  gat_aggregate_w<<<N/4, 256, 0, stream>>>(bufA, offs, ssrc, asrc, adst, bias_conv,
                                           Ah, Al, N);

  // ---- stage 2: l2norm fold -> LN(gat_out @ Wa' + ba) ----
  colnorm_sq_hl<<<dim3(2,128), 256, 0, stream>>>(Ah, Al, ss2, N, 512);
  split_tr_scaled<<<dim3(8,16), 256, 0, stream>>>(Wa, ss2, Bth, Btl, 512, 256);
  gemm_bf16x3<<<dim3(N/128, 4), 256, 0, stream>>>(Ah, Al, Bth, Btl, bufB, N, 256, 512);
  ln_relu_t<256,true><<<N/4, 256, 0, stream>>>(bufB, ba, ga, bga, Ah, Al, N);

  // ---- stage 3 ----
  colnorm_sq<<<dim3(1,128), 256, 0, stream>>>(bufB, ss3, N, 256);
  split_tr_scaled<<<dim3(4,8), 256, 0, stream>>>(W1, ss3, Bth, Btl, 256, 128);
  gemm_bf16x3<<<dim3(N/128, 2), 256, 0, stream>>>(Ah, Al, Bth, Btl, bufA, N, 128, 256);
  ln_relu_t<128,false><<<N/4, 256, 0, stream>>>(bufA, b1, g1, bg1,
                                                (__bf16*)nullptr, (__bf16*)nullptr, N);

  // ---- stage 4 (FUSED): colnorm + [scale W2 + GEMM(16384x64x128) + LN + relu] ----
  colnorm_sq<<<dim3(1,128), 256, 0, stream>>>(bufA, ss4, N, 128);
  gemm64_ln<<<N/4, 256, 0, stream>>>(bufA, W2, ss4, b2, g2, bg2, bufB, N);

  // ---- stage 5: final projection (scale inline) + cdist ----
  colnorm_sq<<<dim3(1,128), 256, 0, stream>>>(bufB, ss5, N, 64);
  final_hf4<<<(N+255)/256, 256, 0, stream>>>(bufB, W3, ss5, b3, hf4, N);
  cdist_kernel<<<dim3(N/1024, N), 256, 0, stream>>>(hf4, outF, N);
}

// Round 10
// 681.763 us; speedup vs baseline: 1.3611x; 1.1244x over previous
//
#include <hip/hip_runtime.h>
#include <math.h>

// ---------------------------------------------------------------------------
// GATNet pipeline, MI355X round 9: round-8 base + cdist 8-row register tiling
// (8x less L2 read amplification) + att/deg_count grid-split fusion (r7-proven).
// ---------------------------------------------------------------------------

typedef __bf16 bf16x8 __attribute__((ext_vector_type(8)));
typedef __bf16 bf16x4 __attribute__((ext_vector_type(4)));
typedef __bf16 bf16x2 __attribute__((ext_vector_type(2)));
typedef float  f32x4  __attribute__((ext_vector_type(4)));
typedef short  short8 __attribute__((ext_vector_type(8)));

static __device__ __forceinline__ float leaky02(float e){ return e >= 0.f ? e : 0.2f*e; }

static __device__ __forceinline__ float wred_sum(float v){
  #pragma unroll
  for (int m = 1; m < 64; m <<= 1) v += __shfl_xor(v, m);
  return v;
}
static __device__ __forceinline__ float wred_max(float v){
  #pragma unroll
  for (int m = 1; m < 64; m <<= 1) v = fmaxf(v, __shfl_xor(v, m));
  return v;
}

// ---------- column sum-of-squares, f32 input ----------
__global__ void colnorm_sq(const float* __restrict__ X, float* __restrict__ ss, int R, int C){
  int c = blockIdx.x*blockDim.x + threadIdx.x;
  if (c >= C) return;
  int r0 = blockIdx.y * 128;
  int r1 = r0 + 128; if (r1 > R) r1 = R;
  float s = 0.f;
  for (int r = r0; r < r1; ++r){ float v = X[(size_t)r*C + c]; s = fmaf(v, v, s); }
  atomicAdd(&ss[c], s);
}

// ---------- column sum-of-squares from bf16 hi/lo pair ----------
__global__ void colnorm_sq_hl(const __bf16* __restrict__ H, const __bf16* __restrict__ L,
                              float* __restrict__ ss, int R, int C){
  int c = blockIdx.x*blockDim.x + threadIdx.x;
  if (c >= C) return;
  int r0 = blockIdx.y * 128;
  int r1 = r0 + 128; if (r1 > R) r1 = R;
  float s = 0.f;
  for (int r = r0; r < r1; ++r){
    float v = (float)H[(size_t)r*C + c] + (float)L[(size_t)r*C + c];
    s = fmaf(v, v, s);
  }
  atomicAdd(&ss[c], s);
}

// ---------- l2norm-scale + split + transpose: W[K][N] -> TH/TL [N][K] bf16 ----------
__global__ __launch_bounds__(256) void split_tr_scaled(const float* __restrict__ B,
    const float* __restrict__ ss,
    __bf16* __restrict__ TH, __bf16* __restrict__ TL, int K, int N){
  __shared__ float tile[32][33];
  int lx = threadIdx.x & 31, ly = threadIdx.x >> 5;
  int kb = blockIdx.y*32, nb = blockIdx.x*32;
  #pragma unroll
  for (int i = 0; i < 4; i++){
    int kr = kb + ly + i*8;
    float inv = 1.f / fmaxf(sqrtf(ss[kr]), 1e-12f);
    tile[ly + i*8][lx] = B[(size_t)kr*N + nb + lx] * inv;
  }
  __syncthreads();
  #pragma unroll
  for (int i = 0; i < 4; i++){
    int nl = ly + i*8;
    float v = tile[lx][nl];
    __bf16 h = (__bf16)v;
    TH[(size_t)(nb + nl)*K + kb + lx] = h;
    TL[(size_t)(nb + nl)*K + kb + lx] = (__bf16)(v - (float)h);
  }
}

// ---------- split-bf16 MFMA GEMM, A pre-split bf16 (3-term) ----------
__global__ __launch_bounds__(256) void gemm_bf16x3(
    const __bf16* __restrict__ Ah, const __bf16* __restrict__ Al,
    const __bf16* __restrict__ Bth, const __bf16* __restrict__ Btl,
    float* __restrict__ C, int M, int N, int K)
{
  __shared__ __align__(16) __bf16 sAh[128][40];
  __shared__ __align__(16) __bf16 sAl[128][40];
  __shared__ __align__(16) __bf16 sBh[64][40];
  __shared__ __align__(16) __bf16 sBl[64][40];
  int tid = threadIdx.x;
  int lane = tid & 63, wave = tid >> 6;
  int wr = wave >> 1, wc = wave & 1;
  int rowBase = blockIdx.x << 7, colBase = blockIdx.y << 6;

  int ar = tid >> 2;
  int ac = tid & 3;

  short8 rAh0, rAh1, rAl0, rAl1, rBh, rBl;
  auto loadA = [&](int k0){
    rAh0 = *(const short8*)(Ah + (size_t)(rowBase + ar     )*K + k0 + ac*8);
    rAh1 = *(const short8*)(Ah + (size_t)(rowBase + ar + 64)*K + k0 + ac*8);
    rAl0 = *(const short8*)(Al + (size_t)(rowBase + ar     )*K + k0 + ac*8);
    rAl1 = *(const short8*)(Al + (size_t)(rowBase + ar + 64)*K + k0 + ac*8);
    rBh  = *(const short8*)(Bth + (size_t)(colBase + ar)*K + k0 + ac*8);
    rBl  = *(const short8*)(Btl + (size_t)(colBase + ar)*K + k0 + ac*8);
  };

  f32x4 acc[4][2];
  #pragma unroll
  for (int m = 0; m < 4; m++)
    #pragma unroll
    for (int n = 0; n < 2; n++) acc[m][n] = (f32x4){0.f,0.f,0.f,0.f};

  loadA(0);
  int nsteps = K >> 5;
  for (int s = 0; s < nsteps; ++s){
    __syncthreads();
    *(short8*)&sAh[ar][ac*8]      = rAh0;
    *(short8*)&sAh[ar+64][ac*8]   = rAh1;
    *(short8*)&sAl[ar][ac*8]      = rAl0;
    *(short8*)&sAl[ar+64][ac*8]   = rAl1;
    *(short8*)&sBh[ar][ac*8]      = rBh;
    *(short8*)&sBl[ar][ac*8]      = rBl;
    if (s + 1 < nsteps) loadA((s+1) << 5);
    __syncthreads();

    int kslot = lane >> 4;
    bf16x8 fah[4], fal[4], fbh[2], fbl[2];
    #pragma unroll
    for (int m = 0; m < 4; m++){
      int r = wr*64 + m*16 + (lane & 15);
      fah[m] = *(const bf16x8*)&sAh[r][kslot*8];
      fal[m] = *(const bf16x8*)&sAl[r][kslot*8];
    }
    #pragma unroll
    for (int n = 0; n < 2; n++){
      int c = wc*32 + n*16 + (lane & 15);
      fbh[n] = *(const bf16x8*)&sBh[c][kslot*8];
      fbl[n] = *(const bf16x8*)&sBl[c][kslot*8];
    }
    #pragma unroll
    for (int m = 0; m < 4; m++)
      #pragma unroll
      for (int n = 0; n < 2; n++){
        acc[m][n] = __builtin_amdgcn_mfma_f32_16x16x32_bf16(fah[m], fbh[n], acc[m][n], 0,0,0);
        acc[m][n] = __builtin_amdgcn_mfma_f32_16x16x32_bf16(fah[m], fbl[n], acc[m][n], 0,0,0);
        acc[m][n] = __builtin_amdgcn_mfma_f32_16x16x32_bf16(fal[m], fbh[n], acc[m][n], 0,0,0);
      }
  }

  int rg = lane >> 4, cl = lane & 15;
  #pragma unroll
  for (int m = 0; m < 4; m++)
    #pragma unroll
    for (int n = 0; n < 2; n++)
      #pragma unroll
      for (int j = 0; j < 4; j++)
        C[(size_t)(rowBase + wr*64 + m*16 + rg*4 + j)*N + colBase + wc*32 + n*16 + cl] = acc[m][n][j];
}

// ---------- same GEMM but A is f32 (stage 1: reads x directly, splits in-reg) ----------
__global__ __launch_bounds__(256) void gemm_f32a_bf16x3(
    const float* __restrict__ A,
    const __bf16* __restrict__ Bth, const __bf16* __restrict__ Btl,
    float* __restrict__ C, int M, int N, int K)
{
  __shared__ __align__(16) __bf16 sAh[128][40];
  __shared__ __align__(16) __bf16 sAl[128][40];
  __shared__ __align__(16) __bf16 sBh[64][40];
  __shared__ __align__(16) __bf16 sBl[64][40];
  int tid = threadIdx.x;
  int lane = tid & 63, wave = tid >> 6;
  int wr = wave >> 1, wc = wave & 1;
  int rowBase = blockIdx.x << 7, colBase = blockIdx.y << 6;

  int ar = tid >> 2;
  int ac = tid & 3;

  float4 rA0a, rA0b, rA1a, rA1b; short8 rBh, rBl;
  auto loadA = [&](int k0){
    const float* p0 = A + (size_t)(rowBase + ar)*K + k0 + ac*8;
    rA0a = *(const float4*)p0; rA0b = *(const float4*)(p0 + 4);
    const float* p1 = A + (size_t)(rowBase + ar + 64)*K + k0 + ac*8;
    rA1a = *(const float4*)p1; rA1b = *(const float4*)(p1 + 4);
    rBh  = *(const short8*)(Bth + (size_t)(colBase + ar)*K + k0 + ac*8);
    rBl  = *(const short8*)(Btl + (size_t)(colBase + ar)*K + k0 + ac*8);
  };
  auto splitst = [&](float4 a, float4 b, __bf16* dh, __bf16* dl){
    float t[8] = {a.x,a.y,a.z,a.w,b.x,b.y,b.z,b.w};
    bf16x8 hv, lv;
    #pragma unroll
    for (int j = 0; j < 8; j++){
      __bf16 h = (__bf16)t[j]; hv[j] = h; lv[j] = (__bf16)(t[j] - (float)h);
    }
    *(bf16x8*)dh = hv; *(bf16x8*)dl = lv;
  };

  f32x4 acc[4][2];
  #pragma unroll
  for (int m = 0; m < 4; m++)
    #pragma unroll
    for (int n = 0; n < 2; n++) acc[m][n] = (f32x4){0.f,0.f,0.f,0.f};

  loadA(0);
  int nsteps = K >> 5;
  for (int s = 0; s < nsteps; ++s){
    __syncthreads();
    splitst(rA0a, rA0b, &sAh[ar][ac*8],    &sAl[ar][ac*8]);
    splitst(rA1a, rA1b, &sAh[ar+64][ac*8], &sAl[ar+64][ac*8]);
    *(short8*)&sBh[ar][ac*8] = rBh;
    *(short8*)&sBl[ar][ac*8] = rBl;
    if (s + 1 < nsteps) loadA((s+1) << 5);
    __syncthreads();

    int kslot = lane >> 4;
    bf16x8 fah[4], fal[4], fbh[2], fbl[2];
    #pragma unroll
    for (int m = 0; m < 4; m++){
      int r = wr*64 + m*16 + (lane & 15);
      fah[m] = *(const bf16x8*)&sAh[r][kslot*8];
      fal[m] = *(const bf16x8*)&sAl[r][kslot*8];
    }
    #pragma unroll
    for (int n = 0; n < 2; n++){
      int c = wc*32 + n*16 + (lane & 15);
      fbh[n] = *(const bf16x8*)&sBh[c][kslot*8];
      fbl[n] = *(const bf16x8*)&sBl[c][kslot*8];
    }
    #pragma unroll
    for (int m = 0; m < 4; m++)
      #pragma unroll
      for (int n = 0; n < 2; n++){
        acc[m][n] = __builtin_amdgcn_mfma_f32_16x16x32_bf16(fah[m], fbh[n], acc[m][n], 0,0,0);
        acc[m][n] = __builtin_amdgcn_mfma_f32_16x16x32_bf16(fah[m], fbl[n], acc[m][n], 0,0,0);
        acc[m][n] = __builtin_amdgcn_mfma_f32_16x16x32_bf16(fal[m], fbh[n], acc[m][n], 0,0,0);
      }
  }

  int rg = lane >> 4, cl = lane & 15;
  #pragma unroll
  for (int m = 0; m < 4; m++)
    #pragma unroll
    for (int n = 0; n < 2; n++)
      #pragma unroll
      for (int j = 0; j < 4; j++)
        C[(size_t)(rowBase + wr*64 + m*16 + rg*4 + j)*N + colBase + wc*32 + n*16 + cl] = acc[m][n][j];
}

// ---------- fused: GAT attention coefficients (wave/node) + degree count ----------
__global__ __launch_bounds__(256) void att_deg_kernel(const float* __restrict__ h,
    const float* __restrict__ att_src, const float* __restrict__ att_dst,
    float* __restrict__ asrc, float* __restrict__ adst,
    const int* __restrict__ dst, int* __restrict__ deg, int nAttBlk, int E){
  if ((int)blockIdx.x < nAttBlk){
    int lane = threadIdx.x & 63;
    int node = blockIdx.x*4 + (threadIdx.x >> 6);
    const float4* hp = (const float4*)(h + (size_t)node*512);
    float4 v0 = hp[lane], v1 = hp[64 + lane];
    float4 as0 = ((const float4*)att_src)[lane], as1 = ((const float4*)att_src)[64+lane];
    float4 ad0 = ((const float4*)att_dst)[lane], ad1 = ((const float4*)att_dst)[64+lane];
    float s0 = v0.x*as0.x + v0.y*as0.y + v0.z*as0.z + v0.w*as0.w;
    float s1 = v1.x*as1.x + v1.y*as1.y + v1.z*as1.z + v1.w*as1.w;
    float d0 = v0.x*ad0.x + v0.y*ad0.y + v0.z*ad0.z + v0.w*ad0.w;
    float d1 = v1.x*ad1.x + v1.y*ad1.y + v1.z*ad1.z + v1.w*ad1.w;
    s0 = wred_sum(s0); s1 = wred_sum(s1); d0 = wred_sum(d0); d1 = wred_sum(d1);
    if (lane == 0){
      asrc[2*node] = s0; asrc[2*node+1] = s1;
      adst[2*node] = d0; adst[2*node+1] = d1;
    }
  } else {
    int e = (blockIdx.x - nAttBlk)*256 + threadIdx.x;
    if (e < E) atomicAdd(&deg[dst[e]], 1);
  }
}

// ---------- CSR build ----------
__global__ __launch_bounds__(1024) void scan_kernel(const int* __restrict__ deg,
    int* __restrict__ offs, int* __restrict__ cursor, int n){
  __shared__ int part[1024];
  int t = threadIdx.x;
  int chunk = (n + 1023) >> 10;
  int base = t * chunk;
  int loc[32];
  int local = 0;
  for (int k = 0; k < chunk; k++){
    int idx = base + k; loc[k] = local;
    if (idx < n) local += deg[idx] + 1;       // +1 self-loop
  }
  part[t] = local; __syncthreads();
  for (int off = 1; off < 1024; off <<= 1){
    int v = (t >= off) ? part[t-off] : 0; __syncthreads();
    part[t] += v; __syncthreads();
  }
  int excl = part[t] - local;
  for (int k = 0; k < chunk; k++){
    int idx = base + k;
    if (idx < n){ int o = excl + loc[k]; offs[idx] = o; cursor[idx] = o; }
  }
  if (t == 1023) offs[n] = part[1023];
}
__global__ void scatter_edges(const int* __restrict__ src, const int* __restrict__ dst,
                              int* cursor, int* __restrict__ ssrc, int E, int N){
  int e = blockIdx.x*blockDim.x + threadIdx.x;
  if (e < E){
    int d = dst[e]; int pos = atomicAdd(&cursor[d], 1); ssrc[pos] = src[e];
  } else if (e < E + N){
    int i = e - E; int pos = atomicAdd(&cursor[i], 1); ssrc[pos] = i;
  }
}

// ---------- GAT aggregation: ONE WAVE per dst node (round-5 proven form) ----------
__global__ __launch_bounds__(256) void gat_aggregate_w(const float* __restrict__ h,
    const int* __restrict__ offs, const int* __restrict__ ssrc,
    const float* __restrict__ asrc, const float* __restrict__ adst,
    const float* __restrict__ bias,
    __bf16* __restrict__ H, __bf16* __restrict__ L, int N){
  int lane = threadIdx.x & 63;
  int d = blockIdx.x*4 + (threadIdx.x >> 6);
  int beg = offs[d], end = offs[d+1], cnt = end - beg;
  float ad0 = adst[2*d], ad1 = adst[2*d+1];

  int dbase = lane*8;                 // this lane owns dims dbase..dbase+7
  bool head0 = dbase < 256;
  f32x4 acc0 = {0.f,0.f,0.f,0.f}, acc1 = {0.f,0.f,0.f,0.f};

  if (cnt <= 64){
    int sreg = 0; float le0 = -1e30f, le1 = -1e30f;
    if (lane < cnt){
      sreg = ssrc[beg + lane];
      float2 a = *(const float2*)&asrc[2*sreg];
      le0 = leaky02(a.x + ad0); le1 = leaky02(a.y + ad1);
    }
    float m0 = wred_max(le0), m1 = wred_max(le1);
    float e0 = (lane < cnt) ? __expf(le0 - m0) : 0.f;
    float e1 = (lane < cnt) ? __expf(le1 - m1) : 0.f;
    float inv0 = 1.f / wred_sum(e0), inv1 = 1.f / wred_sum(e1);
    float al0 = e0*inv0, al1 = e1*inv1;
    for (int o = 0; o < cnt; ++o){
      int s = __shfl(sreg, o);
      float aA = __shfl(al0, o), aB = __shfl(al1, o);
      float al = head0 ? aA : aB;
      const float4* hp = (const float4*)&h[(size_t)s*512 + dbase];
      float4 v0 = hp[0], v1 = hp[1];
      acc0[0] = fmaf(al, v0.x, acc0[0]); acc0[1] = fmaf(al, v0.y, acc0[1]);
      acc0[2] = fmaf(al, v0.z, acc0[2]); acc0[3] = fmaf(al, v0.w, acc0[3]);
      acc1[0] = fmaf(al, v1.x, acc1[0]); acc1[1] = fmaf(al, v1.y, acc1[1]);
      acc1[2] = fmaf(al, v1.z, acc1[2]); acc1[3] = fmaf(al, v1.w, acc1[3]);
    }
  } else {
    float m0 = -1e30f, m1 = -1e30f;
    for (int o = beg + lane; o < end; o += 64){
      int s = ssrc[o]; float2 a = *(const float2*)&asrc[2*s];
      m0 = fmaxf(m0, leaky02(a.x + ad0)); m1 = fmaxf(m1, leaky02(a.y + ad1));
    }
    m0 = wred_max(m0); m1 = wred_max(m1);
    float q0 = 0.f, q1 = 0.f;
    for (int o = beg + lane; o < end; o += 64){
      int s = ssrc[o]; float2 a = *(const float2*)&asrc[2*s];
      q0 += __expf(leaky02(a.x + ad0) - m0); q1 += __expf(leaky02(a.y + ad1) - m1);
    }
    float inv0 = 1.f / wred_sum(q0), inv1 = 1.f / wred_sum(q1);
    for (int c0 = beg; c0 < end; c0 += 64){
      int cc = end - c0; if (cc > 64) cc = 64;
      int sreg = 0; float al0 = 0.f, al1 = 0.f;
      if (lane < cc){
        sreg = ssrc[c0 + lane];
        float2 a = *(const float2*)&asrc[2*sreg];
        al0 = __expf(leaky02(a.x + ad0) - m0) * inv0;
        al1 = __expf(leaky02(a.y + ad1) - m1) * inv1;
      }
      for (int o = 0; o < cc; ++o){
        int s = __shfl(sreg, o);
        float aA = __shfl(al0, o), aB = __shfl(al1, o);
        float al = head0 ? aA : aB;
        const float4* hp = (const float4*)&h[(size_t)s*512 + dbase];
        float4 v0 = hp[0], v1 = hp[1];
        acc0[0] = fmaf(al, v0.x, acc0[0]); acc0[1] = fmaf(al, v0.y, acc0[1]);
        acc0[2] = fmaf(al, v0.z, acc0[2]); acc0[3] = fmaf(al, v0.w, acc0[3]);
        acc1[0] = fmaf(al, v1.x, acc1[0]); acc1[1] = fmaf(al, v1.y, acc1[1]);
        acc1[2] = fmaf(al, v1.z, acc1[2]); acc1[3] = fmaf(al, v1.w, acc1[3]);
      }
    }
  }

  // epilogue: +bias, relu, bf16 hi/lo split, 16B stores
  float4 bi0 = *(const float4*)&bias[dbase];
  float4 bi1 = *(const float4*)&bias[dbase + 4];
  float o_[8];
  o_[0] = fmaxf(acc0[0] + bi0.x, 0.f); o_[1] = fmaxf(acc0[1] + bi0.y, 0.f);
  o_[2] = fmaxf(acc0[2] + bi0.z, 0.f); o_[3] = fmaxf(acc0[3] + bi0.w, 0.f);
  o_[4] = fmaxf(acc1[0] + bi1.x, 0.f); o_[5] = fmaxf(acc1[1] + bi1.y, 0.f);
  o_[6] = fmaxf(acc1[2] + bi1.z, 0.f); o_[7] = fmaxf(acc1[3] + bi1.w, 0.f);
  bf16x8 hv, lv;
  #pragma unroll
  for (int j = 0; j < 8; j++){
    __bf16 hh = (__bf16)o_[j]; hv[j] = hh; lv[j] = (__bf16)(o_[j] - (float)hh);
  }
  *(bf16x8*)&H[(size_t)d*512 + dbase] = hv;
  *(bf16x8*)&L[(size_t)d*512 + dbase] = lv;
}

// ---------- bias + LayerNorm + ReLU, wave per row, optional bf16 split ----------
template<int C, bool SPLIT>
__global__ __launch_bounds__(256) void ln_relu_t(float* __restrict__ Z,
    const float* __restrict__ bias, const float* __restrict__ g,
    const float* __restrict__ bg, __bf16* __restrict__ H, __bf16* __restrict__ L, int R){
  constexpr int VW = C / 64;
  int lane = threadIdx.x & 63, wid = threadIdx.x >> 6;
  int r = blockIdx.x*4 + wid;
  size_t base = (size_t)r*C + lane*VW;
  float v[VW], bi[VW], gm[VW], bt[VW];
  if constexpr (VW == 4){
    float4 t0 = *(const float4*)&Z[base];
    float4 t1 = *(const float4*)&bias[lane*4];
    float4 t2 = *(const float4*)&g[lane*4];
    float4 t3 = *(const float4*)&bg[lane*4];
    v[0]=t0.x; v[1]=t0.y; v[2]=t0.z; v[3]=t0.w;
    bi[0]=t1.x; bi[1]=t1.y; bi[2]=t1.z; bi[3]=t1.w;
    gm[0]=t2.x; gm[1]=t2.y; gm[2]=t2.z; gm[3]=t2.w;
    bt[0]=t3.x; bt[1]=t3.y; bt[2]=t3.z; bt[3]=t3.w;
  } else if constexpr (VW == 2){
    float2 t0 = *(const float2*)&Z[base];
    float2 t1 = *(const float2*)&bias[lane*2];
    float2 t2 = *(const float2*)&g[lane*2];
    float2 t3 = *(const float2*)&bg[lane*2];
    v[0]=t0.x; v[1]=t0.y; bi[0]=t1.x; bi[1]=t1.y;
    gm[0]=t2.x; gm[1]=t2.y; bt[0]=t3.x; bt[1]=t3.y;
  } else {
    v[0] = Z[base]; bi[0] = bias[lane]; gm[0] = g[lane]; bt[0] = bg[lane];
  }
  float sum = 0.f;
  #pragma unroll
  for (int j = 0; j < VW; j++){ v[j] += bi[j]; sum += v[j]; }
  sum = wred_sum(sum);
  float mean = sum * (1.f/C);
  float sq = 0.f;
  #pragma unroll
  for (int j = 0; j < VW; j++){ float dz = v[j]-mean; sq += dz*dz; }
  sq = wred_sum(sq);
  float rs = 1.f / sqrtf(sq*(1.f/C) + 1e-5f);
  float o[VW];
  #pragma unroll
  for (int j = 0; j < VW; j++) o[j] = fmaxf((v[j]-mean)*rs*gm[j] + bt[j], 0.f);
  if constexpr (VW == 4) *(float4*)&Z[base] = make_float4(o[0],o[1],o[2],o[3]);
  else if constexpr (VW == 2) *(float2*)&Z[base] = make_float2(o[0],o[1]);
  else Z[base] = o[0];
  if constexpr (SPLIT){
    if constexpr (VW == 4){
      bf16x4 hv, lv;
      #pragma unroll
      for (int j = 0; j < 4; j++){ hv[j] = (__bf16)o[j]; lv[j] = (__bf16)(o[j]-(float)hv[j]); }
      *(bf16x4*)&H[base] = hv; *(bf16x4*)&L[base] = lv;
    } else if constexpr (VW == 2){
      bf16x2 hv, lv;
      #pragma unroll
      for (int j = 0; j < 2; j++){ hv[j] = (__bf16)o[j]; lv[j] = (__bf16)(o[j]-(float)hv[j]); }
      *(bf16x2*)&H[base] = hv; *(bf16x2*)&L[base] = lv;
    } else {
      __bf16 hv = (__bf16)o[0];
      H[base] = hv; L[base] = (__bf16)(o[0]-(float)hv);
    }
  }
}

// ---------- FUSED stage 4: wave per row, W2 l2norm-scaled in LDS, f32 math ----------
__global__ __launch_bounds__(256) void gemm64_ln(const float* __restrict__ A,
    const float* __restrict__ W2, const float* __restrict__ ss,
    const float* __restrict__ b2, const float* __restrict__ g2,
    const float* __restrict__ bg2, float* __restrict__ Zout, int N){
  __shared__ float w2s[128*64];
  __shared__ float invs[128];
  __shared__ float rowbuf[4][128];
  int t = threadIdx.x;
  int lane = t & 63, wid = t >> 6;
  if (t < 128) invs[t] = 1.f / fmaxf(sqrtf(ss[t]), 1e-12f);
  __syncthreads();
  #pragma unroll
  for (int i = 0; i < 32; i++){
    int idx = t + i*256;
    w2s[idx] = W2[idx] * invs[idx >> 6];
  }
  int r = blockIdx.x*4 + wid;
  float2 rv = *(const float2*)&A[(size_t)r*128 + lane*2];
  rowbuf[wid][lane*2]   = rv.x;
  rowbuf[wid][lane*2+1] = rv.y;
  __syncthreads();
  float acc = b2[lane];
  #pragma unroll 8
  for (int k = 0; k < 128; ++k)
    acc = fmaf(rowbuf[wid][k], w2s[k*64 + lane], acc);
  float mean = wred_sum(acc) * (1.f/64.f);
  float dz = acc - mean;
  float var = wred_sum(dz*dz) * (1.f/64.f);
  float rs = 1.f / sqrtf(var + 1e-5f);
  float o = fmaxf(dz*rs*g2[lane] + bg2[lane], 0.f);
  Zout[(size_t)r*64 + lane] = o;
}

// ---------- final 64->3 GEMM with inline l2norm scale, packs (x,y,z,|h|^2) ----------
__global__ __launch_bounds__(256) void final_hf4(const float* __restrict__ A,
    const float* __restrict__ W3, const float* __restrict__ ss,
    const float* __restrict__ b3, float4* __restrict__ hf4, int N){
  __shared__ float w[64*3];
  __shared__ float b[3];
  if (threadIdx.x < 192){
    int k = threadIdx.x / 3;
    w[threadIdx.x] = W3[threadIdx.x] / fmaxf(sqrtf(ss[k]), 1e-12f);
  }
  if (threadIdx.x < 3) b[threadIdx.x] = b3[threadIdx.x];
  __syncthreads();
  int r = blockIdx.x*blockDim.x + threadIdx.x;
  if (r >= N) return;
  float x = b[0], y = b[1], z = b[2];
  #pragma unroll 8
  for (int k = 0; k < 64; ++k){
    float a = A[(size_t)r*64 + k];
    x = fmaf(a, w[k*3],   x);
    y = fmaf(a, w[k*3+1], y);
    z = fmaf(a, w[k*3+2], z);
  }
  float sq = x*x + y*y + z*z;
  hf4[r] = make_float4(x, y, z, sq);
}

// ---------- cdist v2: 8 rows per block (8x less L2 read amplification) ----------
__global__ __launch_bounds__(256) void cdist_kernel(const float4* __restrict__ hf,
                                                    float* __restrict__ out, int N){
  int i0 = blockIdx.y * 8;
  int j0 = (blockIdx.x*256 + threadIdx.x)*4;
  float4 a[8];
  #pragma unroll
  for (int q = 0; q < 8; q++) a[q] = hf[i0 + q];
  float4 b0 = hf[j0], b1 = hf[j0+1], b2 = hf[j0+2], b3 = hf[j0+3];
  #pragma unroll
  for (int q = 0; q < 8; q++){
    f32x4 r; float d;
    d = a[q].w + b0.w - 2.f*(a[q].x*b0.x + a[q].y*b0.y + a[q].z*b0.z); r[0] = sqrtf(fmaxf(d, 0.f));
    d = a[q].w + b1.w - 2.f*(a[q].x*b1.x + a[q].y*b1.y + a[q].z*b1.z); r[1] = sqrtf(fmaxf(d, 0.f));
    d = a[q].w + b2.w - 2.f*(a[q].x*b2.x + a[q].y*b2.y + a[q].z*b2.z); r[2] = sqrtf(fmaxf(d, 0.f));
    d = a[q].w + b3.w - 2.f*(a[q].x*b3.x + a[q].y*b3.y + a[q].z*b3.z); r[3] = sqrtf(fmaxf(d, 0.f));
    __builtin_nontemporal_store(r, (f32x4*)&out[(size_t)(i0 + q)*N + j0]);
  }
}

// ---------------------------------------------------------------------------
extern "C" void kernel_launch(void* const* d_in, const int* in_sizes, int n_in,
                              void* d_out, int out_size, void* d_ws, size_t ws_size,
                              hipStream_t stream){
  const int N = in_sizes[0] / 512;        // 16384
  const int E = in_sizes[1] / 2;          // 524288

  const float* x         = (const float*)d_in[0];
  const int*   ei        = (const int*)  d_in[1];
  const float* W         = (const float*)d_in[2];
  const float* att_src   = (const float*)d_in[3];
  const float* att_dst   = (const float*)d_in[4];
  const float* bias_conv = (const float*)d_in[5];
  const float* Wa  = (const float*)d_in[6];
  const float* ba  = (const float*)d_in[7];
  const float* ga  = (const float*)d_in[8];
  const float* bga = (const float*)d_in[9];
  const float* W1  = (const float*)d_in[10];
  const float* b1  = (const float*)d_in[11];
  const float* g1  = (const float*)d_in[12];
  const float* bg1 = (const float*)d_in[13];
  const float* W2  = (const float*)d_in[14];
  const float* b2  = (const float*)d_in[15];
  const float* g2  = (const float*)d_in[16];
  const float* bg2 = (const float*)d_in[17];
  const float* W3  = (const float*)d_in[18];
  const float* b3  = (const float*)d_in[19];

  const int* e_src = ei;
  const int* e_dst = ei + E;

  size_t off = 0;
  auto alloc = [&](size_t bytes)->char*{
    size_t o = off; off += (bytes + 255) & ~(size_t)255;
    return (char*)d_ws + o;
  };
  float* bufA  = (float*)alloc((size_t)N*512*4);
  float* bufB  = (float*)alloc((size_t)N*512*4);
  __bf16* Ah   = (__bf16*)alloc((size_t)N*512*2);
  __bf16* Al   = (__bf16*)alloc((size_t)N*512*2);
  __bf16* Bth  = (__bf16*)alloc(512*512*2);
  __bf16* Btl  = (__bf16*)alloc(512*512*2);
  // contiguous zero-init region: 5 ss buffers (512 f32 each) + deg (N ints)
  char* zbase  = alloc(5*512*4 + (size_t)N*4);
  float* ss1 = (float*)zbase;
  float* ss2 = ss1 + 512;
  float* ss3 = ss2 + 512;
  float* ss4 = ss3 + 512;
  float* ss5 = ss4 + 512;
  int*   deg = (int*)(ss5 + 512);
  float* asrc  = (float*)alloc((size_t)N*2*4);
  float* adst  = (float*)alloc((size_t)N*2*4);
  float4* hf4  = (float4*)alloc((size_t)N*16);
  int* offs    = (int*)alloc((size_t)(N+1)*4);
  int* cursor  = (int*)alloc((size_t)N*4);
  int* ssrc    = (int*)alloc((size_t)(E+N)*4);

  float* outF = (float*)d_out;

  hipMemsetAsync(zbase, 0, 5*512*4 + (size_t)N*4, stream);

  // ---- stage 1: l2norm(x) folded into W; h = x @ W' (split fused in staging) ----
  colnorm_sq<<<dim3(2,128), 256, 0, stream>>>(x, ss1, N, 512);
  split_tr_scaled<<<dim3(16,16), 256, 0, stream>>>(W, ss1, Bth, Btl, 512, 512);
  gemm_f32a_bf16x3<<<dim3(N/128, 8), 256, 0, stream>>>(x, Bth, Btl, bufA, N, 512, 512);

  // ---- GAT ----
  int nAttBlk = N/4;
  att_deg_kernel<<<nAttBlk + (E+255)/256, 256, 0, stream>>>(bufA, att_src, att_dst,
                                                            asrc, adst, e_dst, deg, nAttBlk, E);
  scan_kernel<<<1, 1024, 0, stream>>>(deg, offs, cursor, N);
  scatter_edges<<<(E+N+255)/256, 256, 0, stream>>>(e_src, e_dst, cursor, ssrc, E, N);
  gat_aggregate_w<<<N/4, 256, 0, stream>>>(bufA, offs, ssrc, asrc, adst, bias_conv,
                                           Ah, Al, N);

  // ---- stage 2: l2norm fold -> LN(gat_out @ Wa' + ba) ----
  colnorm_sq_hl<<<dim3(2,128), 256, 0, stream>>>(Ah, Al, ss2, N, 512);
  split_tr_scaled<<<dim3(8,16), 256, 0, stream>>>(Wa, ss2, Bth, Btl, 512, 256);
  gemm_bf16x3<<<dim3(N/128, 4), 256, 0, stream>>>(Ah, Al, Bth, Btl, bufB, N, 256, 512);
  ln_relu_t<256,true><<<N/4, 256, 0, stream>>>(bufB, ba, ga, bga, Ah, Al, N);

  // ---- stage 3 ----
  colnorm_sq<<<dim3(1,128), 256, 0, stream>>>(bufB, ss3, N, 256);
  split_tr_scaled<<<dim3(4,8), 256, 0, stream>>>(W1, ss3, Bth, Btl, 256, 128);
  gemm_bf16x3<<<dim3(N/128, 2), 256, 0, stream>>>(Ah, Al, Bth, Btl, bufA, N, 128, 256);
  ln_relu_t<128,false><<<N/4, 256, 0, stream>>>(bufA, b1, g1, bg1,
                                                (__bf16*)nullptr, (__bf16*)nullptr, N);

  // ---- stage 4 (FUSED): colnorm + [scale W2 + GEMM(16384x64x128) + LN + relu] ----
  colnorm_sq<<<dim3(1,128), 256, 0, stream>>>(bufA, ss4, N, 128);
  gemm64_ln<<<N/4, 256, 0, stream>>>(bufA, W2, ss4, b2, g2, bg2, bufB, N);

  // ---- stage 5: final projection (scale inline) + cdist ----
  colnorm_sq<<<dim3(1,128), 256, 0, stream>>>(bufB, ss5, N, 64);
  final_hf4<<<(N+255)/256, 256, 0, stream>>>(bufB, W3, ss5, b3, hf4, N);
  cdist_kernel<<<dim3(N/1024, N/8), 256, 0, stream>>>(hf4, outF, N);
}